// Round 8
// baseline (996.327 us; speedup 1.0000x reference)
//
#include <hip/hip_runtime.h>
#include <hip/hip_fp16.h>
#include <math.h>

#define TID threadIdx.x

typedef ushort u16x8 __attribute__((ext_vector_type(8)));

static constexpr int NN = 20000;
static constexpr int NE = 640000;
static constexpr int NT = 1000000;
static constexpr int C = 128;
static constexpr int E = 64;
static constexpr int LUTN = 4104;     // 4097 live rows + zero padding
static constexpr int NBIN = 1250;     // bins of 16 nodes: 1250*16 = 20000 exactly
static constexpr int NBLK = 128;      // blocks for count/place passes
static constexpr int CHE = 5000;      // NE / NBLK
static constexpr int CHT = 7813;      // ceil(NT / NBLK)
static constexpr float CUT = 5.0f;
static constexpr float LN2 = 0.69314718055994530942f;

__device__ __forceinline__ float ssp(float x) {
    return fmaxf(x, 0.0f) + __logf(1.0f + __expf(-fabsf(x))) - LN2;
}

// softplus WITHOUT the -LN2 (hoisted by caller)
__device__ __forceinline__ float sp_raw(float x) {
    return fmaxf(x, 0.0f) + __logf(1.0f + __expf(-fabsf(x)));
}

__device__ __forceinline__ ushort f2bf(float x) {
    uint u = __float_as_uint(x);
    return (ushort)((u + 0x7FFFu + ((u >> 16) & 1u)) >> 16);
}

__device__ __forceinline__ float bf2f(ushort u) {
    return __uint_as_float((uint)u << 16);
}

__device__ __forceinline__ float h2f(uint bits) {
    return __half2float(__ushort_as_half((ushort)(bits & 0xFFFFu)));
}

// ---- 128x128 GEMM, bf16 weights in LDS, 16 rows per block ----
__global__ __launch_bounds__(256) void k_gemm16f(const float* __restrict__ A,
                                                 const float* __restrict__ W,
                                                 float* __restrict__ out, int nrows) {
    __shared__ ushort wB[C * C];
    __shared__ float aL[16][132];
    for (int i = TID; i < C * C / 4; i += 256) {
        float4 w4 = ((const float4*)W)[i];
        ushort4 u = {f2bf(w4.x), f2bf(w4.y), f2bf(w4.z), f2bf(w4.w)};
        ((ushort4*)wB)[i] = u;
    }
    const int base = blockIdx.x * 16;
    for (int i = TID; i < 512; i += 256) {
        int r = base + (i >> 5);
        float4 v = (r < nrows) ? ((const float4*)A)[(size_t)r * 32 + (i & 31)]
                               : (float4){0.f, 0.f, 0.f, 0.f};
        *(float4*)&aL[i >> 5][(i & 31) << 2] = v;
    }
    __syncthreads();
    const int rg = TID >> 4;
    const int c8 = (TID & 15) << 3;
    float acc[8] = {0.f, 0.f, 0.f, 0.f, 0.f, 0.f, 0.f, 0.f};
    #pragma unroll 8
    for (int k = 0; k < C; ++k) {
        float a = aL[rg][k];
        u16x8 wv = *(const u16x8*)&wB[k * C + c8];
        #pragma unroll
        for (int j = 0; j < 8; ++j) acc[j] = fmaf(a, bf2f(wv[j]), acc[j]);
    }
    int r = base + rg;
    if (r < nrows) {
        float4 o0 = {acc[0], acc[1], acc[2], acc[3]};
        float4 o1 = {acc[4], acc[5], acc[6], acc[7]};
        *(float4*)&out[(size_t)r * C + c8] = o0;
        *(float4*)&out[(size_t)r * C + c8 + 4] = o1;
    }
}

__global__ __launch_bounds__(256) void k_gemm16b(const float* __restrict__ A,
                                                 const float* __restrict__ W,
                                                 ushort* __restrict__ outB, int nrows) {
    __shared__ ushort wB[C * C];
    __shared__ float aL[16][132];
    for (int i = TID; i < C * C / 4; i += 256) {
        float4 w4 = ((const float4*)W)[i];
        ushort4 u = {f2bf(w4.x), f2bf(w4.y), f2bf(w4.z), f2bf(w4.w)};
        ((ushort4*)wB)[i] = u;
    }
    const int base = blockIdx.x * 16;
    for (int i = TID; i < 512; i += 256) {
        int r = base + (i >> 5);
        float4 v = (r < nrows) ? ((const float4*)A)[(size_t)r * 32 + (i & 31)]
                               : (float4){0.f, 0.f, 0.f, 0.f};
        *(float4*)&aL[i >> 5][(i & 31) << 2] = v;
    }
    __syncthreads();
    const int rg = TID >> 4;
    const int c8 = (TID & 15) << 3;
    float acc[8] = {0.f, 0.f, 0.f, 0.f, 0.f, 0.f, 0.f, 0.f};
    #pragma unroll 8
    for (int k = 0; k < C; ++k) {
        float a = aL[rg][k];
        u16x8 wv = *(const u16x8*)&wB[k * C + c8];
        #pragma unroll
        for (int j = 0; j < 8; ++j) acc[j] = fmaf(a, bf2f(wv[j]), acc[j]);
    }
    int r = base + rg;
    if (r < nrows) {
        u16x8 u;
        #pragma unroll
        for (int j = 0; j < 8; ++j) u[j] = f2bf(acc[j]);
        *(u16x8*)&outB[(size_t)r * C + c8] = u;
    }
}

// Build lutB[i][c] = bf16( (ssp(rb(i*delta)@W2b1)@W2b2)[c] ); rows with d>=CUT are 0.
__global__ __launch_bounds__(256) void k_lut(const float* __restrict__ W2b1,
                                             const float* __restrict__ W2b2,
                                             ushort* __restrict__ lutB) {
    __shared__ float w1[E * E];
    __shared__ float w2[E * C];
    __shared__ float rbL[8][E];
    __shared__ float hid[8][E];
    for (int i = TID; i < E * E; i += 256) w1[i] = W2b1[i];
    for (int i = TID; i < E * C; i += 256) w2[i] = W2b2[i];
    const int jj = TID & 63;
    const int esA = TID >> 6;
    const int eg = TID >> 5;
    const int c4 = (TID & 31) << 2;
    const float gamma = 81.92f;
    const float cstep = CUT / 63.0f;
    const float delta = CUT / 4096.0f;
    const int base = blockIdx.x * 8;
    __syncthreads();
    #pragma unroll
    for (int s = 0; s < 2; ++s) {
        int es = esA + 4 * s;
        float d = (float)(base + es) * delta;
        float cv = (d < CUT) ? 0.5f * (1.0f + __cosf((float)M_PI * d / CUT)) : 0.0f;
        float dd = d - (float)jj * cstep;
        rbL[es][jj] = __expf(-gamma * dd * dd) * cv;
    }
    __syncthreads();
    #pragma unroll
    for (int s = 0; s < 2; ++s) {
        int es = esA + 4 * s;
        float a = 0.f;
        #pragma unroll 16
        for (int k = 0; k < E; ++k)
            a = fmaf(rbL[es][k], w1[k * E + jj], a);
        hid[es][jj] = ssp(a);
    }
    __syncthreads();
    float4 o = {0.f, 0.f, 0.f, 0.f};
    #pragma unroll
    for (int j = 0; j < E; ++j) {
        float t = hid[eg][j];
        const float4 w4 = *(const float4*)&w2[j * C + c4];
        o.x = fmaf(t, w4.x, o.x);
        o.y = fmaf(t, w4.y, o.y);
        o.z = fmaf(t, w4.z, o.z);
        o.w = fmaf(t, w4.w, o.w);
    }
    int row = base + eg;
    if (row < LUTN) {
        ushort4 u = {f2bf(o.x), f2bf(o.y), f2bf(o.z), f2bf(o.w)};
        *(ushort4*)&lutB[(size_t)row * C + c4] = u;
    }
}

// Per-block LDS bin histograms (no per-item global atomics).
// cnt tables layout: cnt[k * NBLK + b]
__global__ __launch_bounds__(256) void k_bincount(const int* __restrict__ nl0,
                                                  const int* __restrict__ tidx,
                                                  int* __restrict__ cntE,
                                                  int* __restrict__ cntT) {
    __shared__ int hE[NBIN], hT[NBIN];
    for (int i = TID; i < NBIN; i += 256) { hE[i] = 0; hT[i] = 0; }
    __syncthreads();
    const int b = blockIdx.x;
    const int e0 = b * CHE, e1 = min(e0 + CHE, NE);
    for (int i = e0 + TID; i < e1; i += 256) atomicAdd(&hE[nl0[i] >> 4], 1);
    const int t0 = b * CHT, t1 = min(t0 + CHT, NT);
    for (int i = t0 + TID; i < t1; i += 256) atomicAdd(&hT[tidx[3 * i + 1] >> 4], 1);
    __syncthreads();
    for (int k = TID; k < NBIN; k += 256) {
        cntE[k * NBLK + b] = hE[k];
        cntT[k * NBLK + b] = hT[k];
    }
}

// Per-bin exclusive scan over the 128 blocks; also emits per-bin totals.
__global__ __launch_bounds__(256) void k_rowscan(const int* __restrict__ cE,
                                                 const int* __restrict__ cT,
                                                 int* __restrict__ bE, int* __restrict__ bT,
                                                 int* __restrict__ totE, int* __restrict__ totT) {
    const int lane = TID & 63;
    const int wv = TID >> 6;
    int rid = blockIdx.x * 4 + wv;
    if (rid >= 2 * NBIN) return;
    const int* src = (rid < NBIN) ? cE : cT;
    int* dstB = (rid < NBIN) ? bE : bT;
    int* dstT = (rid < NBIN) ? totE : totT;
    const int k = (rid < NBIN) ? rid : rid - NBIN;
    int v0 = src[k * NBLK + lane];
    int v1 = src[k * NBLK + 64 + lane];
    int a0 = v0, a1 = v1;
    #pragma unroll
    for (int off = 1; off < 64; off <<= 1) {
        int s0 = __shfl_up(a0, off, 64);
        int s1 = __shfl_up(a1, off, 64);
        if (lane >= off) { a0 += s0; a1 += s1; }
    }
    int tot0 = __shfl(a0, 63, 64);
    dstB[k * NBLK + lane] = a0 - v0;
    dstB[k * NBLK + 64 + lane] = tot0 + a1 - v1;
    if (lane == 63) dstT[k] = tot0 + a1;
}

__device__ void scan_one(const int* __restrict__ hist, int* __restrict__ start, int n) {
    __shared__ int wsum[16];
    __shared__ int carryS;
    const int lane = TID & 63;
    const int wv = TID >> 6;
    if (TID == 0) carryS = 0;
    __syncthreads();
    for (int base = 0; base < n; base += 1024) {
        int i = base + TID;
        int v = (i < n) ? hist[i] : 0;
        int acc = v;
        #pragma unroll
        for (int off = 1; off < 64; off <<= 1) {
            int t = __shfl_up(acc, off, 64);
            if (lane >= off) acc += t;
        }
        if (lane == 63) wsum[wv] = acc;
        __syncthreads();
        int woff = 0;
        for (int w = 0; w < wv; ++w) woff += wsum[w];
        int excl = carryS + woff + acc - v;
        if (i < n) start[i] = excl;
        __syncthreads();
        if (TID == 1023) carryS = excl + v;
        __syncthreads();
    }
}

__global__ __launch_bounds__(1024) void k_keyscan(const int* __restrict__ totE, int* __restrict__ startE,
                                                  const int* __restrict__ totT, int* __restrict__ startT) {
    if (blockIdx.x == 0) scan_one(totE, startE, NBIN);
    else                 scan_one(totT, startT, NBIN);
}

// Single-sweep placement via LDS cursors (per-block reserved ranges; no global atomics).
__global__ __launch_bounds__(256) void k_binplace(const int* __restrict__ nl0,
                                                  const int* __restrict__ nl1,
                                                  const float* __restrict__ dist,
                                                  const int* __restrict__ tidx,
                                                  const float* __restrict__ angles,
                                                  const float* __restrict__ rij,
                                                  const float* __restrict__ rik,
                                                  const int* __restrict__ bE,
                                                  const int* __restrict__ bT,
                                                  const int* __restrict__ startE,
                                                  const int* __restrict__ startT,
                                                  int2* __restrict__ eS2,
                                                  int2* __restrict__ tS2) {
    __shared__ int curE[NBIN], curT[NBIN];
    const int b = blockIdx.x;
    for (int k = TID; k < NBIN; k += 256) {
        curE[k] = startE[k] + bE[k * NBLK + b];
        curT[k] = startT[k] + bT[k * NBLK + b];
    }
    __syncthreads();
    const int e0 = b * CHE, e1 = min(e0 + CHE, NE);
    for (int i = e0 + TID; i < e1; i += 256) {
        int n0 = nl0[i];
        int pos = atomicAdd(&curE[n0 >> 4], 1);
        uint tq = (uint)fmaf(dist[i], 209715.2f, 0.5f);   // d * (4096/5) * 256
        eS2[pos] = make_int2((int)tq, nl1[i] | ((n0 & 15) << 16));
    }
    const int t0 = b * CHT, tEnd = min(t0 + CHT, NT);
    for (int i = t0 + TID; i < tEnd; i += 256) {
        int t1 = tidx[3 * i + 1];
        int pos = atomicAdd(&curT[t1 >> 4], 1);
        uint ab = ((uint)__half_as_ushort(__float2half_rn(rik[i])) << 16)
                | (uint)__half_as_ushort(__float2half_rn(rij[i]));
        uint cc = (uint)__half_as_ushort(__float2half_rn(__cosf(angles[i])))
                | ((uint)(t1 & 15) << 16);
        tS2[pos] = make_int2((int)ab, (int)cc);
    }
}

// Edge consume: one block per bin of 16 nodes. LDS accumulation, plain-store rows.
__global__ __launch_bounds__(256) void k_edges_bin(const int2* __restrict__ eS2,
                                                   const int* __restrict__ startE,
                                                   const int* __restrict__ totE,
                                                   const ushort* __restrict__ hB,
                                                   const ushort* __restrict__ lutB,
                                                   float* __restrict__ agg) {
    __shared__ float aggL[16][132];     // padded rows
    __shared__ int2 stage[4][64];
    const int bin = blockIdx.x;
    for (int i = TID; i < 16 * 132; i += 256) ((float*)aggL)[i] = 0.f;
    const int lane = TID & 63;
    const int wv = TID >> 6;
    const int half = lane >> 5;
    const int c4 = (lane & 31) << 2;
    const int s0 = startE[bin];
    const int cnt = totE[bin];
    __syncthreads();
    for (int base = wv * 64; base < cnt; base += 256) {
        const int n = min(64, cnt - base);
        if (lane < n) stage[wv][lane] = eS2[s0 + base + lane];
        asm volatile("s_waitcnt lgkmcnt(0)" ::: "memory");
        for (int j = 0; j < n; j += 2) {
            int my = j + half;
            if (my < n) {
                int2 p = stage[wv][my];
                uint tq = (uint)p.x;
                int n1 = p.y & 0xFFFF;
                int nlo = (p.y >> 16) & 15;
                int idx = min((int)(tq >> 8), LUTN - 2);
                float fr = (float)(tq & 255u) * (1.0f / 256.0f);
                const ushort4 A4 = *(const ushort4*)&lutB[(size_t)idx * C + c4];
                const ushort4 B4 = *(const ushort4*)&lutB[(size_t)(idx + 1) * C + c4];
                const ushort4 hb = *(const ushort4*)&hB[(size_t)n1 * C + c4];
                float ax = bf2f(A4.x), ay = bf2f(A4.y), az = bf2f(A4.z), aw = bf2f(A4.w);
                float ox = fmaf(fr, bf2f(B4.x) - ax, ax) * bf2f(hb.x);
                float oy = fmaf(fr, bf2f(B4.y) - ay, ay) * bf2f(hb.y);
                float oz = fmaf(fr, bf2f(B4.z) - az, az) * bf2f(hb.z);
                float ow = fmaf(fr, bf2f(B4.w) - aw, aw) * bf2f(hb.w);
                atomicAdd(&aggL[nlo][c4 + 0], ox);
                atomicAdd(&aggL[nlo][c4 + 1], oy);
                atomicAdd(&aggL[nlo][c4 + 2], oz);
                atomicAdd(&aggL[nlo][c4 + 3], ow);
            }
        }
        asm volatile("s_waitcnt lgkmcnt(0)" ::: "memory");
    }
    __syncthreads();
    const int nodeBase = bin << 4;
    for (int i = TID; i < 16 * C; i += 256)
        agg[(size_t)(nodeBase + (i >> 7)) * C + (i & 127)] = aggL[i >> 7][i & 127];
}

// Triplet consume: one block per bin. usum[16][64] via LDS float atomics;
// epilogue: w3 = (usum - LN2*cnt) @ W3b2 ; agg[nl0[r]] += h[r]*w3 (atomic: dest random).
__global__ __launch_bounds__(256) void k_trip_bin(const int2* __restrict__ tS2,
                                                  const int* __restrict__ startT,
                                                  const int* __restrict__ totT,
                                                  const float* __restrict__ W3b1,
                                                  const float* __restrict__ W3b2,
                                                  const ushort* __restrict__ hB,
                                                  const int* __restrict__ nl0,
                                                  float* __restrict__ agg) {
    __shared__ float w2[64 * C];     // 32 KB
    __shared__ float usum[16][64];   // 4 KB
    __shared__ int cntL[16];
    __shared__ uint2 stage[4][64];   // 2 KB
    for (int i = TID; i < 64 * C; i += 256) w2[i] = W3b2[i];
    for (int i = TID; i < 16 * 64; i += 256) ((float*)usum)[i] = 0.f;
    if (TID < 16) cntL[TID] = 0;
    const int lane = TID & 63;
    const int wv = TID >> 6;
    const float w1a = W3b1[lane];
    const float w1b = W3b1[64 + lane];
    const float w1c = W3b1[128 + lane];
    const int bin = blockIdx.x;
    const int s0 = startT[bin];
    const int cnt = totT[bin];
    __syncthreads();
    for (int base = wv * 64; base < cnt; base += 256) {
        const int n = min(64, cnt - base);
        if (lane < n) stage[wv][lane] = ((const uint2*)tS2)[s0 + base + lane];
        asm volatile("s_waitcnt lgkmcnt(0)" ::: "memory");
        for (int i = 0; i < n; ++i) {
            uint2 p = stage[wv][i];          // uniform address -> broadcast
            float ri = h2f(p.x);
            float rk = h2f(p.x >> 16);
            float ca = h2f(p.y);
            int nlo = (p.y >> 16) & 15;
            float x = fmaf(ri, w1a, fmaf(rk, w1b, ca * w1c));
            atomicAdd(&usum[nlo][lane], sp_raw(x));
            if (lane == 0) atomicAdd(&cntL[nlo], 1);
        }
        asm volatile("s_waitcnt lgkmcnt(0)" ::: "memory");
    }
    __syncthreads();
    for (int j = wv; j < 16; j += 4) {
        const int r = (bin << 4) + j;
        const float corr = -LN2 * (float)cntL[j];
        float o0 = 0.f, o1 = 0.f;
        #pragma unroll 8
        for (int k = 0; k < 64; ++k) {
            float uk = usum[j][k] + corr;    // uniform LDS read -> broadcast
            o0 = fmaf(uk, w2[k * C + lane], o0);
            o1 = fmaf(uk, w2[k * C + 64 + lane], o1);
        }
        const int n0 = nl0[r];
        float h0 = bf2f(hB[(size_t)r * C + lane]);
        float h1 = bf2f(hB[(size_t)r * C + 64 + lane]);
        unsafeAtomicAdd(&agg[(size_t)n0 * C + lane], o0 * h0);
        unsafeAtomicAdd(&agg[(size_t)n0 * C + 64 + lane], o1 * h1);
    }
}

extern "C" void kernel_launch(void* const* d_in, const int* in_sizes, int n_in,
                              void* d_out, int out_size, void* d_ws, size_t ws_size,
                              hipStream_t stream) {
    const float* features = (const float*)d_in[0];
    const float* ndist    = (const float*)d_in[1];
    const int*   nlist    = (const int*)d_in[2];
    const int*   tidx     = (const int*)d_in[3];
    const float* angles   = (const float*)d_in[4];
    const float* rij      = (const float*)d_in[5];
    const float* rik      = (const float*)d_in[6];
    const float* W_pre    = (const float*)d_in[7];
    const float* W2b1     = (const float*)d_in[8];
    const float* W2b2     = (const float*)d_in[9];
    const float* W3b1     = (const float*)d_in[10];
    const float* W3b2     = (const float*)d_in[11];
    const float* W_post   = (const float*)d_in[12];
    float* out = (float*)d_out;

    char* w = (char*)d_ws;
    float* agg    = (float*)w;   w += (size_t)NN * C * 4;      // 10.24 MB
    ushort* hB    = (ushort*)w;  w += (size_t)NN * C * 2;      // 5.12 MB
    ushort* lutB  = (ushort*)w;  w += (size_t)LUTN * C * 2;    // 1.05 MB
    int2* eS2     = (int2*)w;    w += (size_t)NE * 8;          // 5.12 MB
    int2* tS2     = (int2*)w;    w += (size_t)NT * 8;          // 8 MB
    int* cntE     = (int*)w;     w += (size_t)NBIN * NBLK * 4; // 640 KB
    int* cntT     = (int*)w;     w += (size_t)NBIN * NBLK * 4;
    int* bE       = (int*)w;     w += (size_t)NBIN * NBLK * 4;
    int* bT       = (int*)w;     w += (size_t)NBIN * NBLK * 4;
    int* totE     = (int*)w;     w += (size_t)NBIN * 4;
    int* totT     = (int*)w;     w += (size_t)NBIN * 4;
    int* startE   = (int*)w;     w += (size_t)NBIN * 4;
    int* startT   = (int*)w;     w += (size_t)NBIN * 4;

    const int* nl0 = nlist;
    const int* nl1 = nlist + NE;

    hipLaunchKernelGGL(k_gemm16b, dim3((NN + 15) / 16), dim3(256), 0, stream,
                       features, W_pre, hB, NN);
    hipLaunchKernelGGL(k_lut, dim3((LUTN + 7) / 8), dim3(256), 0, stream,
                       W2b1, W2b2, lutB);
    hipLaunchKernelGGL(k_bincount, dim3(NBLK), dim3(256), 0, stream,
                       nl0, tidx, cntE, cntT);
    hipLaunchKernelGGL(k_rowscan, dim3((2 * NBIN + 3) / 4), dim3(256), 0, stream,
                       cntE, cntT, bE, bT, totE, totT);
    hipLaunchKernelGGL(k_keyscan, dim3(2), dim3(1024), 0, stream,
                       totE, startE, totT, startT);
    hipLaunchKernelGGL(k_binplace, dim3(NBLK), dim3(256), 0, stream,
                       nl0, nl1, ndist, tidx, angles, rij, rik,
                       bE, bT, startE, startT, eS2, tS2);
    hipLaunchKernelGGL(k_edges_bin, dim3(NBIN), dim3(256), 0, stream,
                       eS2, startE, totE, hB, lutB, agg);
    hipLaunchKernelGGL(k_trip_bin, dim3(NBIN), dim3(256), 0, stream,
                       tS2, startT, totT, W3b1, W3b2, hB, nl0, agg);
    hipLaunchKernelGGL(k_gemm16f, dim3((NN + 15) / 16), dim3(256), 0, stream,
                       agg, W_post, out, NN);
}

// Round 9
// 279.462 us; speedup vs baseline: 3.5652x; 3.5652x over previous
//
#include <hip/hip_runtime.h>
#include <hip/hip_fp16.h>
#include <math.h>

#define TID threadIdx.x

typedef ushort u16x8 __attribute__((ext_vector_type(8)));

static constexpr int NN = 20000;
static constexpr int NE = 640000;
static constexpr int NT = 1000000;
static constexpr int C = 128;
static constexpr int E = 64;
static constexpr int LUTN = 4104;     // 4097 live rows + zero padding
static constexpr float CUT = 5.0f;
static constexpr float LN2 = 0.69314718055994530942f;

__device__ __forceinline__ float ssp(float x) {
    return fmaxf(x, 0.0f) + __logf(1.0f + __expf(-fabsf(x))) - LN2;
}

// softplus WITHOUT the -LN2 (hoisted by caller)
__device__ __forceinline__ float sp_raw(float x) {
    return fmaxf(x, 0.0f) + __logf(1.0f + __expf(-fabsf(x)));
}

__device__ __forceinline__ ushort f2bf(float x) {
    uint u = __float_as_uint(x);
    return (ushort)((u + 0x7FFFu + ((u >> 16) & 1u)) >> 16);
}

__device__ __forceinline__ float bf2f(ushort u) {
    return __uint_as_float((uint)u << 16);
}

__device__ __forceinline__ float h2f(uint bits) {
    return __half2float(__ushort_as_half((ushort)(bits & 0xFFFFu)));
}

__global__ __launch_bounds__(256) void k_zero(int* __restrict__ p, int n) {
    int i = blockIdx.x * 256 + TID;
    if (i < n) p[i] = 0;
}

// ---- 128x128 GEMM, bf16 weights in LDS, 16 rows per block ----
__global__ __launch_bounds__(256) void k_gemm16f(const float* __restrict__ A,
                                                 const float* __restrict__ W,
                                                 float* __restrict__ out, int nrows) {
    __shared__ ushort wB[C * C];
    __shared__ float aL[16][132];
    for (int i = TID; i < C * C / 4; i += 256) {
        float4 w4 = ((const float4*)W)[i];
        ushort4 u = {f2bf(w4.x), f2bf(w4.y), f2bf(w4.z), f2bf(w4.w)};
        ((ushort4*)wB)[i] = u;
    }
    const int base = blockIdx.x * 16;
    for (int i = TID; i < 512; i += 256) {
        int r = base + (i >> 5);
        float4 v = (r < nrows) ? ((const float4*)A)[(size_t)r * 32 + (i & 31)]
                               : (float4){0.f, 0.f, 0.f, 0.f};
        *(float4*)&aL[i >> 5][(i & 31) << 2] = v;
    }
    __syncthreads();
    const int rg = TID >> 4;
    const int c8 = (TID & 15) << 3;
    float acc[8] = {0.f, 0.f, 0.f, 0.f, 0.f, 0.f, 0.f, 0.f};
    #pragma unroll 8
    for (int k = 0; k < C; ++k) {
        float a = aL[rg][k];
        u16x8 wv = *(const u16x8*)&wB[k * C + c8];
        #pragma unroll
        for (int j = 0; j < 8; ++j) acc[j] = fmaf(a, bf2f(wv[j]), acc[j]);
    }
    int r = base + rg;
    if (r < nrows) {
        float4 o0 = {acc[0], acc[1], acc[2], acc[3]};
        float4 o1 = {acc[4], acc[5], acc[6], acc[7]};
        *(float4*)&out[(size_t)r * C + c8] = o0;
        *(float4*)&out[(size_t)r * C + c8 + 4] = o1;
    }
}

__global__ __launch_bounds__(256) void k_gemm16b(const float* __restrict__ A,
                                                 const float* __restrict__ W,
                                                 ushort* __restrict__ outB, int nrows) {
    __shared__ ushort wB[C * C];
    __shared__ float aL[16][132];
    for (int i = TID; i < C * C / 4; i += 256) {
        float4 w4 = ((const float4*)W)[i];
        ushort4 u = {f2bf(w4.x), f2bf(w4.y), f2bf(w4.z), f2bf(w4.w)};
        ((ushort4*)wB)[i] = u;
    }
    const int base = blockIdx.x * 16;
    for (int i = TID; i < 512; i += 256) {
        int r = base + (i >> 5);
        float4 v = (r < nrows) ? ((const float4*)A)[(size_t)r * 32 + (i & 31)]
                               : (float4){0.f, 0.f, 0.f, 0.f};
        *(float4*)&aL[i >> 5][(i & 31) << 2] = v;
    }
    __syncthreads();
    const int rg = TID >> 4;
    const int c8 = (TID & 15) << 3;
    float acc[8] = {0.f, 0.f, 0.f, 0.f, 0.f, 0.f, 0.f, 0.f};
    #pragma unroll 8
    for (int k = 0; k < C; ++k) {
        float a = aL[rg][k];
        u16x8 wv = *(const u16x8*)&wB[k * C + c8];
        #pragma unroll
        for (int j = 0; j < 8; ++j) acc[j] = fmaf(a, bf2f(wv[j]), acc[j]);
    }
    int r = base + rg;
    if (r < nrows) {
        u16x8 u;
        #pragma unroll
        for (int j = 0; j < 8; ++j) u[j] = f2bf(acc[j]);
        *(u16x8*)&outB[(size_t)r * C + c8] = u;
    }
}

// Build lutB[i][c] = bf16( (ssp(rb(i*delta)@W2b1)@W2b2)[c] ); rows with d>=CUT are 0.
__global__ __launch_bounds__(256) void k_lut(const float* __restrict__ W2b1,
                                             const float* __restrict__ W2b2,
                                             ushort* __restrict__ lutB) {
    __shared__ float w1[E * E];
    __shared__ float w2[E * C];
    __shared__ float rbL[8][E];
    __shared__ float hid[8][E];
    for (int i = TID; i < E * E; i += 256) w1[i] = W2b1[i];
    for (int i = TID; i < E * C; i += 256) w2[i] = W2b2[i];
    const int jj = TID & 63;
    const int esA = TID >> 6;
    const int eg = TID >> 5;
    const int c4 = (TID & 31) << 2;
    const float gamma = 81.92f;
    const float cstep = CUT / 63.0f;
    const float delta = CUT / 4096.0f;
    const int base = blockIdx.x * 8;
    __syncthreads();
    #pragma unroll
    for (int s = 0; s < 2; ++s) {
        int es = esA + 4 * s;
        float d = (float)(base + es) * delta;
        float cv = (d < CUT) ? 0.5f * (1.0f + __cosf((float)M_PI * d / CUT)) : 0.0f;
        float dd = d - (float)jj * cstep;
        rbL[es][jj] = __expf(-gamma * dd * dd) * cv;
    }
    __syncthreads();
    #pragma unroll
    for (int s = 0; s < 2; ++s) {
        int es = esA + 4 * s;
        float a = 0.f;
        #pragma unroll 16
        for (int k = 0; k < E; ++k)
            a = fmaf(rbL[es][k], w1[k * E + jj], a);
        hid[es][jj] = ssp(a);
    }
    __syncthreads();
    float4 o = {0.f, 0.f, 0.f, 0.f};
    #pragma unroll
    for (int j = 0; j < E; ++j) {
        float t = hid[eg][j];
        const float4 w4 = *(const float4*)&w2[j * C + c4];
        o.x = fmaf(t, w4.x, o.x);
        o.y = fmaf(t, w4.y, o.y);
        o.z = fmaf(t, w4.z, o.z);
        o.w = fmaf(t, w4.w, o.w);
    }
    int row = base + eg;
    if (row < LUTN) {
        ushort4 u = {f2bf(o.x), f2bf(o.y), f2bf(o.z), f2bf(o.w)};
        *(ushort4*)&lutB[(size_t)row * C + c4] = u;
    }
}

// Histogram pass ALSO records each item's arrival rank (enables atomic-free scatter).
__global__ __launch_bounds__(256) void k_hist(const int* __restrict__ nl0,
                                              const int* __restrict__ tidx,
                                              int* __restrict__ histE,
                                              int* __restrict__ histT,
                                              int* __restrict__ rankE,
                                              int* __restrict__ rankT) {
    for (int i = blockIdx.x * 256 + TID; i < NT; i += gridDim.x * 256) {
        if (i < NE) rankE[i] = atomicAdd(&histE[nl0[i]], 1);
        rankT[i] = atomicAdd(&histT[tidx[3 * i + 1]], 1);
    }
}

__device__ void scan_one(const int* __restrict__ hist, int* __restrict__ start, int n) {
    __shared__ int wsum[16];
    __shared__ int carryS;
    const int lane = TID & 63;
    const int wv = TID >> 6;
    if (TID == 0) carryS = 0;
    __syncthreads();
    for (int base = 0; base < n; base += 1024) {
        int i = base + TID;
        int v = (i < n) ? hist[i] : 0;
        int acc = v;
        #pragma unroll
        for (int off = 1; off < 64; off <<= 1) {
            int t = __shfl_up(acc, off, 64);
            if (lane >= off) acc += t;
        }
        if (lane == 63) wsum[wv] = acc;
        __syncthreads();
        int woff = 0;
        for (int w = 0; w < wv; ++w) woff += wsum[w];
        int excl = carryS + woff + acc - v;
        if (i < n) start[i] = excl;
        __syncthreads();
        if (TID == 1023) carryS = excl + v;
        __syncthreads();
    }
}

__global__ __launch_bounds__(1024) void k_scan2(const int* __restrict__ hE, int* __restrict__ sE,
                                                const int* __restrict__ hT, int* __restrict__ sT) {
    if (blockIdx.x == 0) scan_one(hE, sE, NN);
    else                 scan_one(hT, sT, NN);
}

// Atomic-free scatter: pos = start[key] + rank[i]; one 8B store per item.
__global__ __launch_bounds__(256) void k_scatter(const int* __restrict__ nl0,
                                                 const int* __restrict__ nl1,
                                                 const float* __restrict__ dist,
                                                 const int* __restrict__ tidx,
                                                 const float* __restrict__ angles,
                                                 const float* __restrict__ rij,
                                                 const float* __restrict__ rik,
                                                 const int* __restrict__ startE,
                                                 const int* __restrict__ startT,
                                                 const int* __restrict__ rankE,
                                                 const int* __restrict__ rankT,
                                                 int2* __restrict__ eS,
                                                 int2* __restrict__ tS) {
    for (int i = blockIdx.x * 256 + TID; i < NT; i += gridDim.x * 256) {
        if (i < NE) {
            int pos = startE[nl0[i]] + rankE[i];
            // fixed-point LUT coordinate: idx = tq>>8, frac = (tq&255)/256
            uint tq = (uint)fmaf(dist[i], 209715.2f, 0.5f);   // d * (4096/5) * 256
            eS[pos] = make_int2((int)tq, nl1[i]);
        }
        int pos = startT[tidx[3 * i + 1]] + rankT[i];
        uint ab = ((uint)__half_as_ushort(__float2half_rn(rik[i])) << 16)
                | (uint)__half_as_ushort(__float2half_rn(rij[i]));
        uint cc = (uint)__half_as_ushort(__float2half_rn(__cosf(angles[i])));
        tS[pos] = make_int2((int)ab, (int)cc);
    }
}

// Edge consume, wave-per-node: stage the node's edges in a wave-private LDS slot,
// every lane owns 2 contiguous columns, accumulate in registers, plain-store once.
// No output atomics, no n0 array, no agg zeroing needed (writes every row).
__global__ __launch_bounds__(256) void k_edges_node(const int2* __restrict__ eS,
                                                    const int* __restrict__ startE,
                                                    const int* __restrict__ histE,
                                                    const ushort* __restrict__ hB,
                                                    const ushort* __restrict__ lutB,
                                                    float* __restrict__ agg) {
    __shared__ int2 stage[4][64];   // 2 KB, wave-private slots
    const int lane = TID & 63;
    const int wv = TID >> 6;
    const int c2 = lane << 1;       // 2 contiguous cols per lane
    for (int r = blockIdx.x * 4 + wv; r < NN; r += gridDim.x * 4) {
        const int s0 = startE[r];
        const int cnt = histE[r];
        float a0 = 0.f, a1 = 0.f;
        for (int base = 0; base < cnt; base += 64) {
            const int n = min(64, cnt - base);
            if (lane < n) stage[wv][lane] = eS[s0 + base + lane];
            asm volatile("s_waitcnt lgkmcnt(0)" ::: "memory");
            #pragma unroll 4
            for (int i = 0; i < n; ++i) {
                int2 p = stage[wv][i];           // uniform address -> LDS broadcast
                uint tq = (uint)p.x;
                int n1 = p.y;
                int idx = min((int)(tq >> 8), LUTN - 2);
                float fr = (float)(tq & 255u) * (1.0f / 256.0f);
                ushort2 A2 = *(const ushort2*)&lutB[(size_t)idx * C + c2];
                ushort2 B2 = *(const ushort2*)&lutB[(size_t)(idx + 1) * C + c2];
                ushort2 H2 = *(const ushort2*)&hB[(size_t)n1 * C + c2];
                float ax = bf2f(A2.x), ay = bf2f(A2.y);
                float ox = fmaf(fr, bf2f(B2.x) - ax, ax);
                float oy = fmaf(fr, bf2f(B2.y) - ay, ay);
                a0 = fmaf(ox, bf2f(H2.x), a0);
                a1 = fmaf(oy, bf2f(H2.y), a1);
            }
            asm volatile("s_waitcnt lgkmcnt(0)" ::: "memory");  // reads done before overwrite
        }
        float2 o = {a0, a1};
        *(float2*)&agg[(size_t)r * C + c2] = o;
    }
}

// Fused triplet kernel, LDS-broadcast version (adds on top of agg written by edges).
__global__ __launch_bounds__(256) void k_trip_node(const int* __restrict__ startT,
                                                   const int* __restrict__ histT,
                                                   const int2* __restrict__ tS,
                                                   const float* __restrict__ W3b1,
                                                   const float* __restrict__ W3b2,
                                                   const ushort* __restrict__ hB,
                                                   const int* __restrict__ nl0,
                                                   float* __restrict__ agg) {
    __shared__ float w2[64 * C];     // 32 KB
    __shared__ uint2 stage[4][64];   // 2 KB, wave-private slots
    for (int i = TID; i < 64 * C; i += 256) w2[i] = W3b2[i];
    __syncthreads();
    const int lane = TID & 63;
    const int wv = TID >> 6;
    const float w1a = W3b1[lane];
    const float w1b = W3b1[64 + lane];
    const float w1c = W3b1[128 + lane];
    for (int r = blockIdx.x * 4 + wv; r < NN; r += gridDim.x * 4) {
        const int s0 = startT[r];
        const int cnt = histT[r];
        float usum = 0.f;
        for (int base = 0; base < cnt; base += 64) {
            const int n = min(64, cnt - base);
            if (lane < n)
                stage[wv][lane] = ((const uint2*)tS)[s0 + base + lane];
            asm volatile("s_waitcnt lgkmcnt(0)" ::: "memory");
            #pragma unroll 4
            for (int i = 0; i < n; ++i) {
                uint2 p = stage[wv][i];          // uniform address -> broadcast
                float ri = h2f(p.x);
                float rk = h2f(p.x >> 16);
                float ca = h2f(p.y);
                float x = fmaf(ri, w1a, fmaf(rk, w1b, ca * w1c));
                usum += sp_raw(x);
            }
            asm volatile("s_waitcnt lgkmcnt(0)" ::: "memory");
        }
        usum -= LN2 * (float)cnt;
        float o0 = 0.f, o1 = 0.f;
        #pragma unroll 8
        for (int k = 0; k < 64; ++k) {
            float uk = __shfl(usum, k, 64);
            o0 = fmaf(uk, w2[k * C + lane], o0);
            o1 = fmaf(uk, w2[k * C + 64 + lane], o1);
        }
        const int n0 = nl0[r];
        float h0 = bf2f(hB[(size_t)r * C + lane]);
        float h1 = bf2f(hB[(size_t)r * C + 64 + lane]);
        unsafeAtomicAdd(&agg[(size_t)n0 * C + lane], o0 * h0);
        unsafeAtomicAdd(&agg[(size_t)n0 * C + 64 + lane], o1 * h1);
    }
}

extern "C" void kernel_launch(void* const* d_in, const int* in_sizes, int n_in,
                              void* d_out, int out_size, void* d_ws, size_t ws_size,
                              hipStream_t stream) {
    const float* features = (const float*)d_in[0];
    const float* ndist    = (const float*)d_in[1];
    const int*   nlist    = (const int*)d_in[2];
    const int*   tidx     = (const int*)d_in[3];
    const float* angles   = (const float*)d_in[4];
    const float* rij      = (const float*)d_in[5];
    const float* rik      = (const float*)d_in[6];
    const float* W_pre    = (const float*)d_in[7];
    const float* W2b1     = (const float*)d_in[8];
    const float* W2b2     = (const float*)d_in[9];
    const float* W3b1     = (const float*)d_in[10];
    const float* W3b2     = (const float*)d_in[11];
    const float* W_post   = (const float*)d_in[12];
    float* out = (float*)d_out;

    char* w = (char*)d_ws;
    float* agg   = (float*)w;   w += (size_t)NN * C * 4;    // 10.24 MB
    int* histE   = (int*)w;     w += (size_t)NN * 4;
    int* histT   = (int*)w;     w += (size_t)NN * 4;
    ushort* hB   = (ushort*)w;  w += (size_t)NN * C * 2;    // 5.12 MB
    ushort* lutB = (ushort*)w;  w += (size_t)LUTN * C * 2;  // 1.05 MB
    int2* eS     = (int2*)w;    w += (size_t)NE * 8;        // 5.12 MB
    int2* tS     = (int2*)w;    w += (size_t)NT * 8;        // 8 MB
    int* rankE   = (int*)w;     w += (size_t)NE * 4;        // 2.56 MB
    int* rankT   = (int*)w;     w += (size_t)NT * 4;        // 4 MB
    int* startE  = (int*)w;     w += (size_t)NN * 4;
    int* startT  = (int*)w;     w += (size_t)NN * 4;

    const int* nl0 = nlist;
    const int* nl1 = nlist + NE;

    // zero histE + histT (contiguous; agg no longer needs zeroing)
    hipLaunchKernelGGL(k_zero, dim3((2 * NN + 255) / 256), dim3(256), 0, stream,
                       histE, 2 * NN);
    hipLaunchKernelGGL(k_gemm16b, dim3((NN + 15) / 16), dim3(256), 0, stream,
                       features, W_pre, hB, NN);
    hipLaunchKernelGGL(k_lut, dim3((LUTN + 7) / 8), dim3(256), 0, stream,
                       W2b1, W2b2, lutB);
    hipLaunchKernelGGL(k_hist, dim3(2048), dim3(256), 0, stream,
                       nl0, tidx, histE, histT, rankE, rankT);
    hipLaunchKernelGGL(k_scan2, dim3(2), dim3(1024), 0, stream,
                       histE, startE, histT, startT);
    hipLaunchKernelGGL(k_scatter, dim3(2048), dim3(256), 0, stream,
                       nl0, nl1, ndist, tidx, angles, rij, rik,
                       startE, startT, rankE, rankT, eS, tS);
    hipLaunchKernelGGL(k_edges_node, dim3(2500), dim3(256), 0, stream,
                       eS, startE, histE, hB, lutB, agg);
    hipLaunchKernelGGL(k_trip_node, dim3(2500), dim3(256), 0, stream,
                       startT, histT, tS, W3b1, W3b2, hB, nl0, agg);
    hipLaunchKernelGGL(k_gemm16f, dim3((NN + 15) / 16), dim3(256), 0, stream,
                       agg, W_post, out, NN);
}

// Round 10
// 252.470 us; speedup vs baseline: 3.9463x; 1.1069x over previous
//
#include <hip/hip_runtime.h>
#include <hip/hip_fp16.h>
#include <math.h>

#define TID threadIdx.x

typedef ushort u16x8 __attribute__((ext_vector_type(8)));

static constexpr int NN = 20000;
static constexpr int NE = 640000;
static constexpr int NT = 1000000;
static constexpr int C = 128;
static constexpr int E = 64;
static constexpr int LUTN = 4104;     // 4097 live rows + zero padding
static constexpr int NBLK = 128;      // sort blocks
static constexpr int CHE = 5000;      // NE / NBLK
static constexpr int CHT = 7813;      // ceil(NT / NBLK)
static constexpr float CUT = 5.0f;
static constexpr float LN2 = 0.69314718055994530942f;

__device__ __forceinline__ float ssp(float x) {
    return fmaxf(x, 0.0f) + __logf(1.0f + __expf(-fabsf(x))) - LN2;
}

// softplus WITHOUT the -LN2 (hoisted by caller)
__device__ __forceinline__ float sp_raw(float x) {
    return fmaxf(x, 0.0f) + __logf(1.0f + __expf(-fabsf(x)));
}

__device__ __forceinline__ ushort f2bf(float x) {
    uint u = __float_as_uint(x);
    return (ushort)((u + 0x7FFFu + ((u >> 16) & 1u)) >> 16);
}

__device__ __forceinline__ float bf2f(ushort u) {
    return __uint_as_float((uint)u << 16);
}

__device__ __forceinline__ float h2f(uint bits) {
    return __half2float(__ushort_as_half((ushort)(bits & 0xFFFFu)));
}

// ---- 128x128 GEMM, bf16 weights in LDS, 16 rows per block ----
__global__ __launch_bounds__(256) void k_gemm16f(const float* __restrict__ A,
                                                 const float* __restrict__ W,
                                                 float* __restrict__ out, int nrows) {
    __shared__ ushort wB[C * C];
    __shared__ float aL[16][132];
    for (int i = TID; i < C * C / 4; i += 256) {
        float4 w4 = ((const float4*)W)[i];
        ushort4 u = {f2bf(w4.x), f2bf(w4.y), f2bf(w4.z), f2bf(w4.w)};
        ((ushort4*)wB)[i] = u;
    }
    const int base = blockIdx.x * 16;
    for (int i = TID; i < 512; i += 256) {
        int r = base + (i >> 5);
        float4 v = (r < nrows) ? ((const float4*)A)[(size_t)r * 32 + (i & 31)]
                               : (float4){0.f, 0.f, 0.f, 0.f};
        *(float4*)&aL[i >> 5][(i & 31) << 2] = v;
    }
    __syncthreads();
    const int rg = TID >> 4;
    const int c8 = (TID & 15) << 3;
    float acc[8] = {0.f, 0.f, 0.f, 0.f, 0.f, 0.f, 0.f, 0.f};
    #pragma unroll 8
    for (int k = 0; k < C; ++k) {
        float a = aL[rg][k];
        u16x8 wv = *(const u16x8*)&wB[k * C + c8];
        #pragma unroll
        for (int j = 0; j < 8; ++j) acc[j] = fmaf(a, bf2f(wv[j]), acc[j]);
    }
    int r = base + rg;
    if (r < nrows) {
        float4 o0 = {acc[0], acc[1], acc[2], acc[3]};
        float4 o1 = {acc[4], acc[5], acc[6], acc[7]};
        *(float4*)&out[(size_t)r * C + c8] = o0;
        *(float4*)&out[(size_t)r * C + c8 + 4] = o1;
    }
}

__global__ __launch_bounds__(256) void k_gemm16b(const float* __restrict__ A,
                                                 const float* __restrict__ W,
                                                 ushort* __restrict__ outB, int nrows) {
    __shared__ ushort wB[C * C];
    __shared__ float aL[16][132];
    for (int i = TID; i < C * C / 4; i += 256) {
        float4 w4 = ((const float4*)W)[i];
        ushort4 u = {f2bf(w4.x), f2bf(w4.y), f2bf(w4.z), f2bf(w4.w)};
        ((ushort4*)wB)[i] = u;
    }
    const int base = blockIdx.x * 16;
    for (int i = TID; i < 512; i += 256) {
        int r = base + (i >> 5);
        float4 v = (r < nrows) ? ((const float4*)A)[(size_t)r * 32 + (i & 31)]
                               : (float4){0.f, 0.f, 0.f, 0.f};
        *(float4*)&aL[i >> 5][(i & 31) << 2] = v;
    }
    __syncthreads();
    const int rg = TID >> 4;
    const int c8 = (TID & 15) << 3;
    float acc[8] = {0.f, 0.f, 0.f, 0.f, 0.f, 0.f, 0.f, 0.f};
    #pragma unroll 8
    for (int k = 0; k < C; ++k) {
        float a = aL[rg][k];
        u16x8 wv = *(const u16x8*)&wB[k * C + c8];
        #pragma unroll
        for (int j = 0; j < 8; ++j) acc[j] = fmaf(a, bf2f(wv[j]), acc[j]);
    }
    int r = base + rg;
    if (r < nrows) {
        u16x8 u;
        #pragma unroll
        for (int j = 0; j < 8; ++j) u[j] = f2bf(acc[j]);
        *(u16x8*)&outB[(size_t)r * C + c8] = u;
    }
}

// Build lutB[i][c] = bf16( (ssp(rb(i*delta)@W2b1)@W2b2)[c] ); rows with d>=CUT are 0.
__global__ __launch_bounds__(256) void k_lut(const float* __restrict__ W2b1,
                                             const float* __restrict__ W2b2,
                                             ushort* __restrict__ lutB) {
    __shared__ float w1[E * E];
    __shared__ float w2[E * C];
    __shared__ float rbL[8][E];
    __shared__ float hid[8][E];
    for (int i = TID; i < E * E; i += 256) w1[i] = W2b1[i];
    for (int i = TID; i < E * C; i += 256) w2[i] = W2b2[i];
    const int jj = TID & 63;
    const int esA = TID >> 6;
    const int eg = TID >> 5;
    const int c4 = (TID & 31) << 2;
    const float gamma = 81.92f;
    const float cstep = CUT / 63.0f;
    const float delta = CUT / 4096.0f;
    const int base = blockIdx.x * 8;
    __syncthreads();
    #pragma unroll
    for (int s = 0; s < 2; ++s) {
        int es = esA + 4 * s;
        float d = (float)(base + es) * delta;
        float cv = (d < CUT) ? 0.5f * (1.0f + __cosf((float)M_PI * d / CUT)) : 0.0f;
        float dd = d - (float)jj * cstep;
        rbL[es][jj] = __expf(-gamma * dd * dd) * cv;
    }
    __syncthreads();
    #pragma unroll
    for (int s = 0; s < 2; ++s) {
        int es = esA + 4 * s;
        float a = 0.f;
        #pragma unroll 16
        for (int k = 0; k < E; ++k)
            a = fmaf(rbL[es][k], w1[k * E + jj], a);
        hid[es][jj] = ssp(a);
    }
    __syncthreads();
    float4 o = {0.f, 0.f, 0.f, 0.f};
    #pragma unroll
    for (int j = 0; j < E; ++j) {
        float t = hid[eg][j];
        const float4 w4 = *(const float4*)&w2[j * C + c4];
        o.x = fmaf(t, w4.x, o.x);
        o.y = fmaf(t, w4.y, o.y);
        o.z = fmaf(t, w4.z, o.z);
        o.w = fmaf(t, w4.w, o.w);
    }
    int row = base + eg;
    if (row < LUTN) {
        ushort4 u = {f2bf(o.x), f2bf(o.y), f2bf(o.z), f2bf(o.w)};
        *(ushort4*)&lutB[(size_t)row * C + c4] = u;
    }
}

// Per-block exact-node histograms via LDS (no global atomics).
// cnt layout: cnt[b * NN + k], ushort (per-node-per-block counts are tiny).
__global__ __launch_bounds__(256) void k_count(const int* __restrict__ nl0,
                                               const int* __restrict__ tidx,
                                               ushort* __restrict__ cntE,
                                               ushort* __restrict__ cntT) {
    __shared__ int h[NN];   // 78.1 KB
    const int b = blockIdx.x;
    for (int i = TID; i < NN; i += 256) h[i] = 0;
    __syncthreads();
    const int e0 = b * CHE, e1 = min(e0 + CHE, NE);
    for (int i = e0 + TID; i < e1; i += 256) atomicAdd(&h[nl0[i]], 1);
    __syncthreads();
    for (int i = TID; i < NN; i += 256) cntE[(size_t)b * NN + i] = (ushort)h[i];
    __syncthreads();
    for (int i = TID; i < NN; i += 256) h[i] = 0;
    __syncthreads();
    const int t0 = b * CHT, t1 = min(t0 + CHT, NT);
    for (int i = t0 + TID; i < t1; i += 256) atomicAdd(&h[tidx[3 * i + 1]], 1);
    __syncthreads();
    for (int i = TID; i < NN; i += 256) cntT[(size_t)b * NN + i] = (ushort)h[i];
}

// Per-node exclusive scan across the NBLK blocks -> bE/bT (ushort) + totals (int).
__global__ __launch_bounds__(256) void k_rowscan(const ushort* __restrict__ cE,
                                                 const ushort* __restrict__ cT,
                                                 ushort* __restrict__ bE,
                                                 ushort* __restrict__ bT,
                                                 int* __restrict__ totE,
                                                 int* __restrict__ totT) {
    const int lane = TID & 63;
    const int wv = TID >> 6;
    const int ngrp = (NN + 63) / 64;          // 313
    int task = blockIdx.x * 4 + wv;
    if (task >= 2 * ngrp) return;
    const bool isE = task < ngrp;
    const ushort* src = isE ? cE : cT;
    ushort* dstB = isE ? bE : bT;
    int* dstT = isE ? totE : totT;
    int k = (isE ? task : task - ngrp) * 64 + lane;
    if (k >= NN) return;
    int acc = 0;
    for (int b = 0; b < NBLK; ++b) {
        size_t off = (size_t)b * NN + k;
        int v = src[off];
        dstB[off] = (ushort)acc;
        acc += v;
    }
    dstT[k] = acc;
}

__device__ void scan_one(const int* __restrict__ hist, int* __restrict__ start, int n) {
    __shared__ int wsum[16];
    __shared__ int carryS;
    const int lane = TID & 63;
    const int wv = TID >> 6;
    if (TID == 0) carryS = 0;
    __syncthreads();
    for (int base = 0; base < n; base += 1024) {
        int i = base + TID;
        int v = (i < n) ? hist[i] : 0;
        int acc = v;
        #pragma unroll
        for (int off = 1; off < 64; off <<= 1) {
            int t = __shfl_up(acc, off, 64);
            if (lane >= off) acc += t;
        }
        if (lane == 63) wsum[wv] = acc;
        __syncthreads();
        int woff = 0;
        for (int w = 0; w < wv; ++w) woff += wsum[w];
        int excl = carryS + woff + acc - v;
        if (i < n) start[i] = excl;
        __syncthreads();
        if (TID == 1023) carryS = excl + v;
        __syncthreads();
    }
}

__global__ __launch_bounds__(1024) void k_keyscan(const int* __restrict__ totE, int* __restrict__ startE,
                                                  const int* __restrict__ totT, int* __restrict__ startT) {
    if (blockIdx.x == 0) scan_one(totE, startE, NN);
    else                 scan_one(totT, startT, NN);
}

// Placement with exact-node LDS cursors (no global atomics; scattered 8B payload stores).
__global__ __launch_bounds__(256) void k_place(const int* __restrict__ nl0,
                                               const int* __restrict__ nl1,
                                               const float* __restrict__ dist,
                                               const int* __restrict__ tidx,
                                               const float* __restrict__ angles,
                                               const float* __restrict__ rij,
                                               const float* __restrict__ rik,
                                               const ushort* __restrict__ bE,
                                               const ushort* __restrict__ bT,
                                               const int* __restrict__ startE,
                                               const int* __restrict__ startT,
                                               int2* __restrict__ eS,
                                               int2* __restrict__ tS) {
    __shared__ int cur[NN];   // 78.1 KB
    const int b = blockIdx.x;
    for (int k = TID; k < NN; k += 256)
        cur[k] = startE[k] + (int)bE[(size_t)b * NN + k];
    __syncthreads();
    const int e0 = b * CHE, e1 = min(e0 + CHE, NE);
    for (int i = e0 + TID; i < e1; i += 256) {
        int pos = atomicAdd(&cur[nl0[i]], 1);
        // fixed-point LUT coordinate: idx = tq>>8, frac = (tq&255)/256
        uint tq = (uint)fmaf(dist[i], 209715.2f, 0.5f);   // d * (4096/5) * 256
        eS[pos] = make_int2((int)tq, nl1[i]);
    }
    __syncthreads();
    for (int k = TID; k < NN; k += 256)
        cur[k] = startT[k] + (int)bT[(size_t)b * NN + k];
    __syncthreads();
    const int t0 = b * CHT, tEnd = min(t0 + CHT, NT);
    for (int i = t0 + TID; i < tEnd; i += 256) {
        int t1 = tidx[3 * i + 1];
        int pos = atomicAdd(&cur[t1], 1);
        uint ab = ((uint)__half_as_ushort(__float2half_rn(rik[i])) << 16)
                | (uint)__half_as_ushort(__float2half_rn(rij[i]));
        uint cc = (uint)__half_as_ushort(__float2half_rn(__cosf(angles[i])));
        tS[pos] = make_int2((int)ab, (int)cc);
    }
}

// Edge consume, wave-per-node: stage the node's edges in a wave-private LDS slot,
// every lane owns 2 contiguous columns, accumulate in registers, plain-store once.
__global__ __launch_bounds__(256) void k_edges_node(const int2* __restrict__ eS,
                                                    const int* __restrict__ startE,
                                                    const int* __restrict__ totE,
                                                    const ushort* __restrict__ hB,
                                                    const ushort* __restrict__ lutB,
                                                    float* __restrict__ agg) {
    __shared__ int2 stage[4][64];   // 2 KB, wave-private slots
    const int lane = TID & 63;
    const int wv = TID >> 6;
    const int c2 = lane << 1;       // 2 contiguous cols per lane
    for (int r = blockIdx.x * 4 + wv; r < NN; r += gridDim.x * 4) {
        const int s0 = startE[r];
        const int cnt = totE[r];
        float a0 = 0.f, a1 = 0.f;
        for (int base = 0; base < cnt; base += 64) {
            const int n = min(64, cnt - base);
            if (lane < n) stage[wv][lane] = eS[s0 + base + lane];
            asm volatile("s_waitcnt lgkmcnt(0)" ::: "memory");
            #pragma unroll 4
            for (int i = 0; i < n; ++i) {
                int2 p = stage[wv][i];           // uniform address -> LDS broadcast
                uint tq = (uint)p.x;
                int n1 = p.y;
                int idx = min((int)(tq >> 8), LUTN - 2);
                float fr = (float)(tq & 255u) * (1.0f / 256.0f);
                ushort2 A2 = *(const ushort2*)&lutB[(size_t)idx * C + c2];
                ushort2 B2 = *(const ushort2*)&lutB[(size_t)(idx + 1) * C + c2];
                ushort2 H2 = *(const ushort2*)&hB[(size_t)n1 * C + c2];
                float ax = bf2f(A2.x), ay = bf2f(A2.y);
                float ox = fmaf(fr, bf2f(B2.x) - ax, ax);
                float oy = fmaf(fr, bf2f(B2.y) - ay, ay);
                a0 = fmaf(ox, bf2f(H2.x), a0);
                a1 = fmaf(oy, bf2f(H2.y), a1);
            }
            asm volatile("s_waitcnt lgkmcnt(0)" ::: "memory");  // reads done before overwrite
        }
        float2 o = {a0, a1};
        *(float2*)&agg[(size_t)r * C + c2] = o;
    }
}

// Fused triplet kernel, LDS-broadcast version (adds on top of agg written by edges).
__global__ __launch_bounds__(256) void k_trip_node(const int* __restrict__ startT,
                                                   const int* __restrict__ totT,
                                                   const int2* __restrict__ tS,
                                                   const float* __restrict__ W3b1,
                                                   const float* __restrict__ W3b2,
                                                   const ushort* __restrict__ hB,
                                                   const int* __restrict__ nl0,
                                                   float* __restrict__ agg) {
    __shared__ float w2[64 * C];     // 32 KB
    __shared__ uint2 stage[4][64];   // 2 KB, wave-private slots
    for (int i = TID; i < 64 * C; i += 256) w2[i] = W3b2[i];
    __syncthreads();
    const int lane = TID & 63;
    const int wv = TID >> 6;
    const float w1a = W3b1[lane];
    const float w1b = W3b1[64 + lane];
    const float w1c = W3b1[128 + lane];
    for (int r = blockIdx.x * 4 + wv; r < NN; r += gridDim.x * 4) {
        const int s0 = startT[r];
        const int cnt = totT[r];
        float usum = 0.f;
        for (int base = 0; base < cnt; base += 64) {
            const int n = min(64, cnt - base);
            if (lane < n)
                stage[wv][lane] = ((const uint2*)tS)[s0 + base + lane];
            asm volatile("s_waitcnt lgkmcnt(0)" ::: "memory");
            #pragma unroll 4
            for (int i = 0; i < n; ++i) {
                uint2 p = stage[wv][i];          // uniform address -> broadcast
                float ri = h2f(p.x);
                float rk = h2f(p.x >> 16);
                float ca = h2f(p.y);
                float x = fmaf(ri, w1a, fmaf(rk, w1b, ca * w1c));
                usum += sp_raw(x);
            }
            asm volatile("s_waitcnt lgkmcnt(0)" ::: "memory");
        }
        usum -= LN2 * (float)cnt;
        float o0 = 0.f, o1 = 0.f;
        #pragma unroll 8
        for (int k = 0; k < 64; ++k) {
            float uk = __shfl(usum, k, 64);
            o0 = fmaf(uk, w2[k * C + lane], o0);
            o1 = fmaf(uk, w2[k * C + 64 + lane], o1);
        }
        const int n0 = nl0[r];
        float h0 = bf2f(hB[(size_t)r * C + lane]);
        float h1 = bf2f(hB[(size_t)r * C + 64 + lane]);
        unsafeAtomicAdd(&agg[(size_t)n0 * C + lane], o0 * h0);
        unsafeAtomicAdd(&agg[(size_t)n0 * C + 64 + lane], o1 * h1);
    }
}

extern "C" void kernel_launch(void* const* d_in, const int* in_sizes, int n_in,
                              void* d_out, int out_size, void* d_ws, size_t ws_size,
                              hipStream_t stream) {
    const float* features = (const float*)d_in[0];
    const float* ndist    = (const float*)d_in[1];
    const int*   nlist    = (const int*)d_in[2];
    const int*   tidx     = (const int*)d_in[3];
    const float* angles   = (const float*)d_in[4];
    const float* rij      = (const float*)d_in[5];
    const float* rik      = (const float*)d_in[6];
    const float* W_pre    = (const float*)d_in[7];
    const float* W2b1     = (const float*)d_in[8];
    const float* W2b2     = (const float*)d_in[9];
    const float* W3b1     = (const float*)d_in[10];
    const float* W3b2     = (const float*)d_in[11];
    const float* W_post   = (const float*)d_in[12];
    float* out = (float*)d_out;

    char* w = (char*)d_ws;
    // agg (10.24 MB) aliases cntE+cntT (5.12 MB each): cnt dead before agg is written.
    float* agg    = (float*)w;
    ushort* cntE  = (ushort*)w;
    ushort* cntT  = (ushort*)(w + (size_t)NN * NBLK * 2);
    w += (size_t)NN * C * 4;                                  // 10.24 MB
    ushort* hB    = (ushort*)w;  w += (size_t)NN * C * 2;     // 5.12 MB
    ushort* lutB  = (ushort*)w;  w += (size_t)LUTN * C * 2;   // 1.05 MB
    int2* eS      = (int2*)w;    w += (size_t)NE * 8;         // 5.12 MB
    int2* tS      = (int2*)w;    w += (size_t)NT * 8;         // 8 MB
    ushort* bE    = (ushort*)w;  w += (size_t)NN * NBLK * 2;  // 5.12 MB
    ushort* bT    = (ushort*)w;  w += (size_t)NN * NBLK * 2;  // 5.12 MB
    int* totE     = (int*)w;     w += (size_t)NN * 4;
    int* totT     = (int*)w;     w += (size_t)NN * 4;
    int* startE   = (int*)w;     w += (size_t)NN * 4;
    int* startT   = (int*)w;     w += (size_t)NN * 4;

    const int* nl0 = nlist;
    const int* nl1 = nlist + NE;

    hipLaunchKernelGGL(k_gemm16b, dim3((NN + 15) / 16), dim3(256), 0, stream,
                       features, W_pre, hB, NN);
    hipLaunchKernelGGL(k_lut, dim3((LUTN + 7) / 8), dim3(256), 0, stream,
                       W2b1, W2b2, lutB);
    hipLaunchKernelGGL(k_count, dim3(NBLK), dim3(256), 0, stream,
                       nl0, tidx, cntE, cntT);
    hipLaunchKernelGGL(k_rowscan, dim3((2 * ((NN + 63) / 64) + 3) / 4), dim3(256), 0, stream,
                       cntE, cntT, bE, bT, totE, totT);
    hipLaunchKernelGGL(k_keyscan, dim3(2), dim3(1024), 0, stream,
                       totE, startE, totT, startT);
    hipLaunchKernelGGL(k_place, dim3(NBLK), dim3(256), 0, stream,
                       nl0, nl1, ndist, tidx, angles, rij, rik,
                       bE, bT, startE, startT, eS, tS);
    hipLaunchKernelGGL(k_edges_node, dim3(2500), dim3(256), 0, stream,
                       eS, startE, totE, hB, lutB, agg);
    hipLaunchKernelGGL(k_trip_node, dim3(2500), dim3(256), 0, stream,
                       startT, totT, tS, W3b1, W3b2, hB, nl0, agg);
    hipLaunchKernelGGL(k_gemm16f, dim3((NN + 15) / 16), dim3(256), 0, stream,
                       agg, W_post, out, NN);
}

// Round 11
// 194.061 us; speedup vs baseline: 5.1341x; 1.3010x over previous
//
#include <hip/hip_runtime.h>
#include <hip/hip_fp16.h>
#include <math.h>

#define TID threadIdx.x

typedef ushort u16x8 __attribute__((ext_vector_type(8)));
typedef unsigned char uchar;

static constexpr int NN = 20000;
static constexpr int NE = 640000;
static constexpr int NT = 1000000;
static constexpr int C = 128;
static constexpr int E = 64;
static constexpr int LUTN = 4104;     // 4097 live rows + zero padding
static constexpr int NBKT = 313;      // buckets of 64 nodes (313*64 = 20032)
static constexpr int NB2 = 512;       // sort blocks
static constexpr int CHE2 = 1250;     // NE / 512
static constexpr int CHT2 = 1954;     // ceil(NT / 512)
static constexpr float CUT = 5.0f;
static constexpr float LN2 = 0.69314718055994530942f;

__device__ __forceinline__ float ssp(float x) {
    return fmaxf(x, 0.0f) + __logf(1.0f + __expf(-fabsf(x))) - LN2;
}

// softplus WITHOUT the -LN2 (hoisted by caller)
__device__ __forceinline__ float sp_raw(float x) {
    return fmaxf(x, 0.0f) + __logf(1.0f + __expf(-fabsf(x)));
}

__device__ __forceinline__ ushort f2bf(float x) {
    uint u = __float_as_uint(x);
    return (ushort)((u + 0x7FFFu + ((u >> 16) & 1u)) >> 16);
}

__device__ __forceinline__ float bf2f(ushort u) {
    return __uint_as_float((uint)u << 16);
}

__device__ __forceinline__ float h2f(uint bits) {
    return __half2float(__ushort_as_half((ushort)(bits & 0xFFFFu)));
}

// ---- 128x128 GEMM, bf16 weights in LDS, 16 rows per block ----
__global__ __launch_bounds__(256) void k_gemm16f(const float* __restrict__ A,
                                                 const float* __restrict__ W,
                                                 float* __restrict__ out, int nrows) {
    __shared__ ushort wB[C * C];
    __shared__ float aL[16][132];
    for (int i = TID; i < C * C / 4; i += 256) {
        float4 w4 = ((const float4*)W)[i];
        ushort4 u = {f2bf(w4.x), f2bf(w4.y), f2bf(w4.z), f2bf(w4.w)};
        ((ushort4*)wB)[i] = u;
    }
    const int base = blockIdx.x * 16;
    for (int i = TID; i < 512; i += 256) {
        int r = base + (i >> 5);
        float4 v = (r < nrows) ? ((const float4*)A)[(size_t)r * 32 + (i & 31)]
                               : (float4){0.f, 0.f, 0.f, 0.f};
        *(float4*)&aL[i >> 5][(i & 31) << 2] = v;
    }
    __syncthreads();
    const int rg = TID >> 4;
    const int c8 = (TID & 15) << 3;
    float acc[8] = {0.f, 0.f, 0.f, 0.f, 0.f, 0.f, 0.f, 0.f};
    #pragma unroll 8
    for (int k = 0; k < C; ++k) {
        float a = aL[rg][k];
        u16x8 wv = *(const u16x8*)&wB[k * C + c8];
        #pragma unroll
        for (int j = 0; j < 8; ++j) acc[j] = fmaf(a, bf2f(wv[j]), acc[j]);
    }
    int r = base + rg;
    if (r < nrows) {
        float4 o0 = {acc[0], acc[1], acc[2], acc[3]};
        float4 o1 = {acc[4], acc[5], acc[6], acc[7]};
        *(float4*)&out[(size_t)r * C + c8] = o0;
        *(float4*)&out[(size_t)r * C + c8 + 4] = o1;
    }
}

__global__ __launch_bounds__(256) void k_gemm16b(const float* __restrict__ A,
                                                 const float* __restrict__ W,
                                                 ushort* __restrict__ outB, int nrows) {
    __shared__ ushort wB[C * C];
    __shared__ float aL[16][132];
    for (int i = TID; i < C * C / 4; i += 256) {
        float4 w4 = ((const float4*)W)[i];
        ushort4 u = {f2bf(w4.x), f2bf(w4.y), f2bf(w4.z), f2bf(w4.w)};
        ((ushort4*)wB)[i] = u;
    }
    const int base = blockIdx.x * 16;
    for (int i = TID; i < 512; i += 256) {
        int r = base + (i >> 5);
        float4 v = (r < nrows) ? ((const float4*)A)[(size_t)r * 32 + (i & 31)]
                               : (float4){0.f, 0.f, 0.f, 0.f};
        *(float4*)&aL[i >> 5][(i & 31) << 2] = v;
    }
    __syncthreads();
    const int rg = TID >> 4;
    const int c8 = (TID & 15) << 3;
    float acc[8] = {0.f, 0.f, 0.f, 0.f, 0.f, 0.f, 0.f, 0.f};
    #pragma unroll 8
    for (int k = 0; k < C; ++k) {
        float a = aL[rg][k];
        u16x8 wv = *(const u16x8*)&wB[k * C + c8];
        #pragma unroll
        for (int j = 0; j < 8; ++j) acc[j] = fmaf(a, bf2f(wv[j]), acc[j]);
    }
    int r = base + rg;
    if (r < nrows) {
        u16x8 u;
        #pragma unroll
        for (int j = 0; j < 8; ++j) u[j] = f2bf(acc[j]);
        *(u16x8*)&outB[(size_t)r * C + c8] = u;
    }
}

// Build lutB[i][c] = bf16( (ssp(rb(i*delta)@W2b1)@W2b2)[c] ); rows with d>=CUT are 0.
__global__ __launch_bounds__(256) void k_lut(const float* __restrict__ W2b1,
                                             const float* __restrict__ W2b2,
                                             ushort* __restrict__ lutB) {
    __shared__ float w1[E * E];
    __shared__ float w2[E * C];
    __shared__ float rbL[8][E];
    __shared__ float hid[8][E];
    for (int i = TID; i < E * E; i += 256) w1[i] = W2b1[i];
    for (int i = TID; i < E * C; i += 256) w2[i] = W2b2[i];
    const int jj = TID & 63;
    const int esA = TID >> 6;
    const int eg = TID >> 5;
    const int c4 = (TID & 31) << 2;
    const float gamma = 81.92f;
    const float cstep = CUT / 63.0f;
    const float delta = CUT / 4096.0f;
    const int base = blockIdx.x * 8;
    __syncthreads();
    #pragma unroll
    for (int s = 0; s < 2; ++s) {
        int es = esA + 4 * s;
        float d = (float)(base + es) * delta;
        float cv = (d < CUT) ? 0.5f * (1.0f + __cosf((float)M_PI * d / CUT)) : 0.0f;
        float dd = d - (float)jj * cstep;
        rbL[es][jj] = __expf(-gamma * dd * dd) * cv;
    }
    __syncthreads();
    #pragma unroll
    for (int s = 0; s < 2; ++s) {
        int es = esA + 4 * s;
        float a = 0.f;
        #pragma unroll 16
        for (int k = 0; k < E; ++k)
            a = fmaf(rbL[es][k], w1[k * E + jj], a);
        hid[es][jj] = ssp(a);
    }
    __syncthreads();
    float4 o = {0.f, 0.f, 0.f, 0.f};
    #pragma unroll
    for (int j = 0; j < E; ++j) {
        float t = hid[eg][j];
        const float4 w4 = *(const float4*)&w2[j * C + c4];
        o.x = fmaf(t, w4.x, o.x);
        o.y = fmaf(t, w4.y, o.y);
        o.z = fmaf(t, w4.z, o.z);
        o.w = fmaf(t, w4.w, o.w);
    }
    int row = base + eg;
    if (row < LUTN) {
        ushort4 u = {f2bf(o.x), f2bf(o.y), f2bf(o.z), f2bf(o.w)};
        *(ushort4*)&lutB[(size_t)row * C + c4] = u;
    }
}

// Per-block bucket histograms (tiny LDS, full occupancy, no global atomics).
// cnt layout: cnt[k * NB2 + b], u8.
__global__ __launch_bounds__(256) void k_bcount(const int* __restrict__ nl0,
                                                const int* __restrict__ tidx,
                                                uchar* __restrict__ cntE,
                                                uchar* __restrict__ cntT) {
    __shared__ int h[NBKT];
    const int b = blockIdx.x;
    for (int i = TID; i < NBKT; i += 256) h[i] = 0;
    __syncthreads();
    const int e0 = b * CHE2, e1 = min(e0 + CHE2, NE);
    for (int i = e0 + TID; i < e1; i += 256) atomicAdd(&h[nl0[i] >> 6], 1);
    __syncthreads();
    for (int i = TID; i < NBKT; i += 256) { cntE[(size_t)i * NB2 + b] = (uchar)h[i]; h[i] = 0; }
    __syncthreads();
    const int t0 = b * CHT2, t1 = min(t0 + CHT2, NT);
    for (int i = t0 + TID; i < t1; i += 256) atomicAdd(&h[tidx[3 * i + 1] >> 6], 1);
    __syncthreads();
    for (int i = TID; i < NBKT; i += 256) cntT[(size_t)i * NB2 + b] = (uchar)h[i];
}

// Per-bucket exclusive scan across the 512 blocks -> bases (ushort) + bucket totals (int).
__global__ __launch_bounds__(256) void k_bscan(const uchar* __restrict__ cE,
                                               const uchar* __restrict__ cT,
                                               ushort* __restrict__ baseE,
                                               ushort* __restrict__ baseT,
                                               int* __restrict__ totEb,
                                               int* __restrict__ totTb) {
    const int lane = TID & 63;
    const int wv = TID >> 6;
    int task = blockIdx.x * 4 + wv;
    if (task >= 2 * NBKT) return;
    const bool isE = task < NBKT;
    const int k = isE ? task : task - NBKT;
    const uchar* src = isE ? cE : cT;
    ushort* dst = isE ? baseE : baseT;
    int* dT = isE ? totEb : totTb;
    int v[8], pre[8], s = 0;
    #pragma unroll
    for (int j = 0; j < 8; ++j) {
        v[j] = src[(size_t)k * NB2 + lane * 8 + j];
        pre[j] = s;
        s += v[j];
    }
    int incl = s;
    #pragma unroll
    for (int off = 1; off < 64; off <<= 1) {
        int t = __shfl_up(incl, off, 64);
        if (lane >= off) incl += t;
    }
    int excl = incl - s;
    #pragma unroll
    for (int j = 0; j < 8; ++j)
        dst[(size_t)k * NB2 + lane * 8 + j] = (ushort)(excl + pre[j]);
    if (lane == 63) dT[k] = incl;
}

__device__ void scan_one(const int* __restrict__ hist, int* __restrict__ start, int n) {
    __shared__ int wsum[16];
    __shared__ int carryS;
    const int lane = TID & 63;
    const int wv = TID >> 6;
    if (TID == 0) carryS = 0;
    __syncthreads();
    for (int base = 0; base < n; base += 1024) {
        int i = base + TID;
        int v = (i < n) ? hist[i] : 0;
        int acc = v;
        #pragma unroll
        for (int off = 1; off < 64; off <<= 1) {
            int t = __shfl_up(acc, off, 64);
            if (lane >= off) acc += t;
        }
        if (lane == 63) wsum[wv] = acc;
        __syncthreads();
        int woff = 0;
        for (int w = 0; w < wv; ++w) woff += wsum[w];
        int excl = carryS + woff + acc - v;
        if (i < n) start[i] = excl;
        __syncthreads();
        if (TID == 1023) carryS = excl + v;
        __syncthreads();
    }
}

__global__ __launch_bounds__(1024) void k_bktscan(const int* __restrict__ totEb, int* __restrict__ bksE,
                                                  const int* __restrict__ totTb, int* __restrict__ bksT) {
    if (blockIdx.x == 0) scan_one(totEb, bksE, NBKT);
    else                 scan_one(totTb, bksT, NBKT);
}

// Phase-1 placement into bucket regions. 1.25 KB LDS cursors, 512 blocks, full occupancy.
// Each block's items for one bucket land contiguously -> near-coalesced stores.
// Node-within-bucket (6 bits) stashed in payload spare bits.
__global__ __launch_bounds__(256) void k_bplace(const int* __restrict__ nl0,
                                                const int* __restrict__ nl1,
                                                const float* __restrict__ dist,
                                                const int* __restrict__ tidx,
                                                const float* __restrict__ angles,
                                                const float* __restrict__ rij,
                                                const float* __restrict__ rik,
                                                const ushort* __restrict__ baseE,
                                                const ushort* __restrict__ baseT,
                                                const int* __restrict__ bksE,
                                                const int* __restrict__ bksT,
                                                int2* __restrict__ eT,
                                                int2* __restrict__ tT) {
    __shared__ int cur[NBKT];
    const int b = blockIdx.x;
    for (int k = TID; k < NBKT; k += 256)
        cur[k] = bksE[k] + (int)baseE[(size_t)k * NB2 + b];
    __syncthreads();
    const int e0 = b * CHE2, e1 = min(e0 + CHE2, NE);
    for (int i = e0 + TID; i < e1; i += 256) {
        int n0 = nl0[i];
        int pos = atomicAdd(&cur[n0 >> 6], 1);
        // fixed-point LUT coordinate in 26 bits; nlo6 in bits 26-31
        uint tq = (uint)fmaf(dist[i], 209715.2f, 0.5f);   // d * (4096/5) * 256
        eT[pos] = make_int2((int)(tq | ((uint)(n0 & 63) << 26)), nl1[i]);
    }
    __syncthreads();
    for (int k = TID; k < NBKT; k += 256)
        cur[k] = bksT[k] + (int)baseT[(size_t)k * NB2 + b];
    __syncthreads();
    const int t0 = b * CHT2, tEnd = min(t0 + CHT2, NT);
    for (int i = t0 + TID; i < tEnd; i += 256) {
        int t1 = tidx[3 * i + 1];
        int pos = atomicAdd(&cur[t1 >> 6], 1);
        uint ab = ((uint)__half_as_ushort(__float2half_rn(rik[i])) << 16)
                | (uint)__half_as_ushort(__float2half_rn(rij[i]));
        uint cc = (uint)__half_as_ushort(__float2half_rn(__cosf(angles[i])))
                | ((uint)(t1 & 63) << 16);
        tT[pos] = make_int2((int)ab, (int)cc);
    }
}

// Phase-2: per bucket, exact node sort within the bucket window (L2-resident scatter).
// Also emits per-node start/tot for the consumers. grid: [0,NBKT)=E, [NBKT,2*NBKT)=T.
__global__ __launch_bounds__(256) void k_nsort(const int2* __restrict__ eTs,
                                               const int2* __restrict__ tTs,
                                               const int* __restrict__ bksE,
                                               const int* __restrict__ bksT,
                                               const int* __restrict__ totEb,
                                               const int* __restrict__ totTb,
                                               int2* __restrict__ eS,
                                               int2* __restrict__ tS,
                                               int* __restrict__ startE,
                                               int* __restrict__ totE,
                                               int* __restrict__ startT,
                                               int* __restrict__ totT) {
    __shared__ int hist[64];
    __shared__ int cur[64];
    const bool isE = blockIdx.x < NBKT;
    const int bkt = isE ? blockIdx.x : blockIdx.x - NBKT;
    const int2* src = isE ? eTs : tTs;
    int2* dst = isE ? eS : tS;
    const int s0 = isE ? bksE[bkt] : bksT[bkt];
    const int cnt = isE ? totEb[bkt] : totTb[bkt];
    int* stX = isE ? startE : startT;
    int* ttX = isE ? totE : totT;
    if (TID < 64) hist[TID] = 0;
    __syncthreads();
    for (int i = TID; i < cnt; i += 256) {
        int2 p = src[s0 + i];
        int nlo = isE ? (int)(((uint)p.x >> 26) & 63u) : (int)(((uint)p.y >> 16) & 63u);
        atomicAdd(&hist[nlo], 1);
    }
    __syncthreads();
    if (TID < 64) {                    // exactly wave 0
        int v = hist[TID];
        int incl = v;
        #pragma unroll
        for (int off = 1; off < 64; off <<= 1) {
            int t = __shfl_up(incl, off, 64);
            if (TID >= off) incl += t;
        }
        int excl = incl - v;
        cur[TID] = s0 + excl;
        int node = bkt * 64 + TID;
        if (node < NN) { stX[node] = s0 + excl; ttX[node] = v; }
    }
    __syncthreads();
    for (int i = TID; i < cnt; i += 256) {
        int2 p = src[s0 + i];
        int nlo = isE ? (int)(((uint)p.x >> 26) & 63u) : (int)(((uint)p.y >> 16) & 63u);
        int pos = atomicAdd(&cur[nlo], 1);
        dst[pos] = p;
    }
}

// Edge consume, wave-per-node (unchanged except 26-bit tq mask).
__global__ __launch_bounds__(256) void k_edges_node(const int2* __restrict__ eS,
                                                    const int* __restrict__ startE,
                                                    const int* __restrict__ totE,
                                                    const ushort* __restrict__ hB,
                                                    const ushort* __restrict__ lutB,
                                                    float* __restrict__ agg) {
    __shared__ int2 stage[4][64];   // 2 KB, wave-private slots
    const int lane = TID & 63;
    const int wv = TID >> 6;
    const int c2 = lane << 1;       // 2 contiguous cols per lane
    for (int r = blockIdx.x * 4 + wv; r < NN; r += gridDim.x * 4) {
        const int s0 = startE[r];
        const int cnt = totE[r];
        float a0 = 0.f, a1 = 0.f;
        for (int base = 0; base < cnt; base += 64) {
            const int n = min(64, cnt - base);
            if (lane < n) stage[wv][lane] = eS[s0 + base + lane];
            asm volatile("s_waitcnt lgkmcnt(0)" ::: "memory");
            #pragma unroll 4
            for (int i = 0; i < n; ++i) {
                int2 p = stage[wv][i];           // uniform address -> LDS broadcast
                uint tq = ((uint)p.x) & 0x03FFFFFFu;
                int n1 = p.y;
                int idx = min((int)(tq >> 8), LUTN - 2);
                float fr = (float)(tq & 255u) * (1.0f / 256.0f);
                ushort2 A2 = *(const ushort2*)&lutB[(size_t)idx * C + c2];
                ushort2 B2 = *(const ushort2*)&lutB[(size_t)(idx + 1) * C + c2];
                ushort2 H2 = *(const ushort2*)&hB[(size_t)n1 * C + c2];
                float ax = bf2f(A2.x), ay = bf2f(A2.y);
                float ox = fmaf(fr, bf2f(B2.x) - ax, ax);
                float oy = fmaf(fr, bf2f(B2.y) - ay, ay);
                a0 = fmaf(ox, bf2f(H2.x), a0);
                a1 = fmaf(oy, bf2f(H2.y), a1);
            }
            asm volatile("s_waitcnt lgkmcnt(0)" ::: "memory");  // reads done before overwrite
        }
        float2 o = {a0, a1};
        *(float2*)&agg[(size_t)r * C + c2] = o;
    }
}

// Fused triplet kernel (unchanged; ca reads low 16 bits, nlo junk above is masked by h2f).
__global__ __launch_bounds__(256) void k_trip_node(const int* __restrict__ startT,
                                                   const int* __restrict__ totT,
                                                   const int2* __restrict__ tS,
                                                   const float* __restrict__ W3b1,
                                                   const float* __restrict__ W3b2,
                                                   const ushort* __restrict__ hB,
                                                   const int* __restrict__ nl0,
                                                   float* __restrict__ agg) {
    __shared__ float w2[64 * C];     // 32 KB
    __shared__ uint2 stage[4][64];   // 2 KB, wave-private slots
    for (int i = TID; i < 64 * C; i += 256) w2[i] = W3b2[i];
    __syncthreads();
    const int lane = TID & 63;
    const int wv = TID >> 6;
    const float w1a = W3b1[lane];
    const float w1b = W3b1[64 + lane];
    const float w1c = W3b1[128 + lane];
    for (int r = blockIdx.x * 4 + wv; r < NN; r += gridDim.x * 4) {
        const int s0 = startT[r];
        const int cnt = totT[r];
        float usum = 0.f;
        for (int base = 0; base < cnt; base += 64) {
            const int n = min(64, cnt - base);
            if (lane < n)
                stage[wv][lane] = ((const uint2*)tS)[s0 + base + lane];
            asm volatile("s_waitcnt lgkmcnt(0)" ::: "memory");
            #pragma unroll 4
            for (int i = 0; i < n; ++i) {
                uint2 p = stage[wv][i];          // uniform address -> broadcast
                float ri = h2f(p.x);
                float rk = h2f(p.x >> 16);
                float ca = h2f(p.y);
                float x = fmaf(ri, w1a, fmaf(rk, w1b, ca * w1c));
                usum += sp_raw(x);
            }
            asm volatile("s_waitcnt lgkmcnt(0)" ::: "memory");
        }
        usum -= LN2 * (float)cnt;
        float o0 = 0.f, o1 = 0.f;
        #pragma unroll 8
        for (int k = 0; k < 64; ++k) {
            float uk = __shfl(usum, k, 64);
            o0 = fmaf(uk, w2[k * C + lane], o0);
            o1 = fmaf(uk, w2[k * C + 64 + lane], o1);
        }
        const int n0 = nl0[r];
        float h0 = bf2f(hB[(size_t)r * C + lane]);
        float h1 = bf2f(hB[(size_t)r * C + 64 + lane]);
        unsafeAtomicAdd(&agg[(size_t)n0 * C + lane], o0 * h0);
        unsafeAtomicAdd(&agg[(size_t)n0 * C + 64 + lane], o1 * h1);
    }
}

extern "C" void kernel_launch(void* const* d_in, const int* in_sizes, int n_in,
                              void* d_out, int out_size, void* d_ws, size_t ws_size,
                              hipStream_t stream) {
    const float* features = (const float*)d_in[0];
    const float* ndist    = (const float*)d_in[1];
    const int*   nlist    = (const int*)d_in[2];
    const int*   tidx     = (const int*)d_in[3];
    const float* angles   = (const float*)d_in[4];
    const float* rij      = (const float*)d_in[5];
    const float* rik      = (const float*)d_in[6];
    const float* W_pre    = (const float*)d_in[7];
    const float* W2b1     = (const float*)d_in[8];
    const float* W2b2     = (const float*)d_in[9];
    const float* W3b1     = (const float*)d_in[10];
    const float* W3b2     = (const float*)d_in[11];
    const float* W_post   = (const float*)d_in[12];
    float* out = (float*)d_out;

    char* w = (char*)d_ws;
    // agg (10.24 MB) region: first 5.12 MB aliases eT (dead before agg is written)
    float* agg    = (float*)w;
    int2* eT      = (int2*)w;
    w += (size_t)NN * C * 4;                                   // 10.24 MB
    ushort* hB    = (ushort*)w;  w += (size_t)NN * C * 2;      // 5.12 MB
    ushort* lutB  = (ushort*)w;  w += (size_t)LUTN * C * 2;    // 1.05 MB
    int2* eS      = (int2*)w;    w += (size_t)NE * 8;          // 5.12 MB
    int2* tS      = (int2*)w;    w += (size_t)NT * 8;          // 8 MB
    int2* tT      = (int2*)w;    w += (size_t)NT * 8;          // 8 MB
    uchar* cntE   = (uchar*)w;   w += (size_t)NBKT * NB2;      // 160 KB
    uchar* cntT   = (uchar*)w;   w += (size_t)NBKT * NB2;
    ushort* baseE = (ushort*)w;  w += (size_t)NBKT * NB2 * 2;  // 320 KB
    ushort* baseT = (ushort*)w;  w += (size_t)NBKT * NB2 * 2;
    int* totEb    = (int*)w;     w += 1280;
    int* totTb    = (int*)w;     w += 1280;
    int* bksE     = (int*)w;     w += 1280;
    int* bksT     = (int*)w;     w += 1280;
    int* startE   = (int*)w;     w += (size_t)NN * 4;
    int* totE     = (int*)w;     w += (size_t)NN * 4;
    int* startT   = (int*)w;     w += (size_t)NN * 4;
    int* totT     = (int*)w;     w += (size_t)NN * 4;

    const int* nl0 = nlist;
    const int* nl1 = nlist + NE;

    hipLaunchKernelGGL(k_gemm16b, dim3((NN + 15) / 16), dim3(256), 0, stream,
                       features, W_pre, hB, NN);
    hipLaunchKernelGGL(k_lut, dim3((LUTN + 7) / 8), dim3(256), 0, stream,
                       W2b1, W2b2, lutB);
    hipLaunchKernelGGL(k_bcount, dim3(NB2), dim3(256), 0, stream,
                       nl0, tidx, cntE, cntT);
    hipLaunchKernelGGL(k_bscan, dim3((2 * NBKT + 3) / 4), dim3(256), 0, stream,
                       cntE, cntT, baseE, baseT, totEb, totTb);
    hipLaunchKernelGGL(k_bktscan, dim3(2), dim3(1024), 0, stream,
                       totEb, bksE, totTb, bksT);
    hipLaunchKernelGGL(k_bplace, dim3(NB2), dim3(256), 0, stream,
                       nl0, nl1, ndist, tidx, angles, rij, rik,
                       baseE, baseT, bksE, bksT, eT, tT);
    hipLaunchKernelGGL(k_nsort, dim3(2 * NBKT), dim3(256), 0, stream,
                       eT, tT, bksE, bksT, totEb, totTb,
                       eS, tS, startE, totE, startT, totT);
    hipLaunchKernelGGL(k_edges_node, dim3(2500), dim3(256), 0, stream,
                       eS, startE, totE, hB, lutB, agg);
    hipLaunchKernelGGL(k_trip_node, dim3(2500), dim3(256), 0, stream,
                       startT, totT, tS, W3b1, W3b2, hB, nl0, agg);
    hipLaunchKernelGGL(k_gemm16f, dim3((NN + 15) / 16), dim3(256), 0, stream,
                       agg, W_post, out, NN);
}

// Round 12
// 192.041 us; speedup vs baseline: 5.1881x; 1.0105x over previous
//
#include <hip/hip_runtime.h>
#include <hip/hip_fp16.h>
#include <math.h>

#define TID threadIdx.x

typedef ushort u16x8 __attribute__((ext_vector_type(8)));
typedef unsigned char uchar;

static constexpr int NN = 20000;
static constexpr int NE = 640000;
static constexpr int NT = 1000000;
static constexpr int C = 128;
static constexpr int E = 64;
static constexpr int LUTN = 4104;     // 4097 live rows + zero padding
static constexpr int NBKT = 313;      // buckets of 64 nodes (313*64 = 20032)
static constexpr int NB2 = 512;       // sort blocks
static constexpr int CHE2 = 1250;     // NE / 512
static constexpr int CHT2 = 1954;     // ceil(NT / 512)
static constexpr float CUT = 5.0f;
static constexpr float LN2 = 0.69314718055994530942f;

__device__ __forceinline__ float ssp(float x) {
    return fmaxf(x, 0.0f) + __logf(1.0f + __expf(-fabsf(x))) - LN2;
}

__device__ __forceinline__ ushort f2bf(float x) {
    uint u = __float_as_uint(x);
    return (ushort)((u + 0x7FFFu + ((u >> 16) & 1u)) >> 16);
}

__device__ __forceinline__ float bf2f(ushort u) {
    return __uint_as_float((uint)u << 16);
}

__device__ __forceinline__ float h2f(uint bits) {
    return __half2float(__ushort_as_half((ushort)(bits & 0xFFFFu)));
}

// ---- 128x128 GEMM, bf16 weights in LDS, 16 rows per block ----
__global__ __launch_bounds__(256) void k_gemm16f(const float* __restrict__ A,
                                                 const float* __restrict__ W,
                                                 float* __restrict__ out, int nrows) {
    __shared__ ushort wB[C * C];
    __shared__ float aL[16][132];
    for (int i = TID; i < C * C / 4; i += 256) {
        float4 w4 = ((const float4*)W)[i];
        ushort4 u = {f2bf(w4.x), f2bf(w4.y), f2bf(w4.z), f2bf(w4.w)};
        ((ushort4*)wB)[i] = u;
    }
    const int base = blockIdx.x * 16;
    for (int i = TID; i < 512; i += 256) {
        int r = base + (i >> 5);
        float4 v = (r < nrows) ? ((const float4*)A)[(size_t)r * 32 + (i & 31)]
                               : (float4){0.f, 0.f, 0.f, 0.f};
        *(float4*)&aL[i >> 5][(i & 31) << 2] = v;
    }
    __syncthreads();
    const int rg = TID >> 4;
    const int c8 = (TID & 15) << 3;
    float acc[8] = {0.f, 0.f, 0.f, 0.f, 0.f, 0.f, 0.f, 0.f};
    #pragma unroll 8
    for (int k = 0; k < C; ++k) {
        float a = aL[rg][k];
        u16x8 wv = *(const u16x8*)&wB[k * C + c8];
        #pragma unroll
        for (int j = 0; j < 8; ++j) acc[j] = fmaf(a, bf2f(wv[j]), acc[j]);
    }
    int r = base + rg;
    if (r < nrows) {
        float4 o0 = {acc[0], acc[1], acc[2], acc[3]};
        float4 o1 = {acc[4], acc[5], acc[6], acc[7]};
        *(float4*)&out[(size_t)r * C + c8] = o0;
        *(float4*)&out[(size_t)r * C + c8 + 4] = o1;
    }
}

__global__ __launch_bounds__(256) void k_gemm16b(const float* __restrict__ A,
                                                 const float* __restrict__ W,
                                                 ushort* __restrict__ outB, int nrows) {
    __shared__ ushort wB[C * C];
    __shared__ float aL[16][132];
    for (int i = TID; i < C * C / 4; i += 256) {
        float4 w4 = ((const float4*)W)[i];
        ushort4 u = {f2bf(w4.x), f2bf(w4.y), f2bf(w4.z), f2bf(w4.w)};
        ((ushort4*)wB)[i] = u;
    }
    const int base = blockIdx.x * 16;
    for (int i = TID; i < 512; i += 256) {
        int r = base + (i >> 5);
        float4 v = (r < nrows) ? ((const float4*)A)[(size_t)r * 32 + (i & 31)]
                               : (float4){0.f, 0.f, 0.f, 0.f};
        *(float4*)&aL[i >> 5][(i & 31) << 2] = v;
    }
    __syncthreads();
    const int rg = TID >> 4;
    const int c8 = (TID & 15) << 3;
    float acc[8] = {0.f, 0.f, 0.f, 0.f, 0.f, 0.f, 0.f, 0.f};
    #pragma unroll 8
    for (int k = 0; k < C; ++k) {
        float a = aL[rg][k];
        u16x8 wv = *(const u16x8*)&wB[k * C + c8];
        #pragma unroll
        for (int j = 0; j < 8; ++j) acc[j] = fmaf(a, bf2f(wv[j]), acc[j]);
    }
    int r = base + rg;
    if (r < nrows) {
        u16x8 u;
        #pragma unroll
        for (int j = 0; j < 8; ++j) u[j] = f2bf(acc[j]);
        *(u16x8*)&outB[(size_t)r * C + c8] = u;
    }
}

// Build lutB (radial LUT, bf16) and spLut (softplus-correction LUT, float2 {v, dv}).
__global__ __launch_bounds__(256) void k_lut(const float* __restrict__ W2b1,
                                             const float* __restrict__ W2b2,
                                             ushort* __restrict__ lutB,
                                             float2* __restrict__ spLut) {
    if (blockIdx.x == (LUTN + 7) / 8) {
        // g(t) = log1p(exp(-t)), t in [0,16], 512 intervals
        for (int e = TID; e < 512; e += 256) {
            float t0 = (float)e * (1.0f / 32.0f);
            float t1 = (float)(e + 1) * (1.0f / 32.0f);
            float v0 = log1pf(__expf(-t0));
            float v1 = log1pf(__expf(-t1));
            spLut[e] = make_float2(v0, v1 - v0);
        }
        return;
    }
    __shared__ float w1[E * E];
    __shared__ float w2[E * C];
    __shared__ float rbL[8][E];
    __shared__ float hid[8][E];
    for (int i = TID; i < E * E; i += 256) w1[i] = W2b1[i];
    for (int i = TID; i < E * C; i += 256) w2[i] = W2b2[i];
    const int jj = TID & 63;
    const int esA = TID >> 6;
    const int eg = TID >> 5;
    const int c4 = (TID & 31) << 2;
    const float gamma = 81.92f;
    const float cstep = CUT / 63.0f;
    const float delta = CUT / 4096.0f;
    const int base = blockIdx.x * 8;
    __syncthreads();
    #pragma unroll
    for (int s = 0; s < 2; ++s) {
        int es = esA + 4 * s;
        float d = (float)(base + es) * delta;
        float cv = (d < CUT) ? 0.5f * (1.0f + __cosf((float)M_PI * d / CUT)) : 0.0f;
        float dd = d - (float)jj * cstep;
        rbL[es][jj] = __expf(-gamma * dd * dd) * cv;
    }
    __syncthreads();
    #pragma unroll
    for (int s = 0; s < 2; ++s) {
        int es = esA + 4 * s;
        float a = 0.f;
        #pragma unroll 16
        for (int k = 0; k < E; ++k)
            a = fmaf(rbL[es][k], w1[k * E + jj], a);
        hid[es][jj] = ssp(a);
    }
    __syncthreads();
    float4 o = {0.f, 0.f, 0.f, 0.f};
    #pragma unroll
    for (int j = 0; j < E; ++j) {
        float t = hid[eg][j];
        const float4 w4 = *(const float4*)&w2[j * C + c4];
        o.x = fmaf(t, w4.x, o.x);
        o.y = fmaf(t, w4.y, o.y);
        o.z = fmaf(t, w4.z, o.z);
        o.w = fmaf(t, w4.w, o.w);
    }
    int row = base + eg;
    if (row < LUTN) {
        ushort4 u = {f2bf(o.x), f2bf(o.y), f2bf(o.z), f2bf(o.w)};
        *(ushort4*)&lutB[(size_t)row * C + c4] = u;
    }
}

// Per-block bucket histograms (tiny LDS, full occupancy, no global atomics).
__global__ __launch_bounds__(256) void k_bcount(const int* __restrict__ nl0,
                                                const int* __restrict__ tidx,
                                                uchar* __restrict__ cntE,
                                                uchar* __restrict__ cntT) {
    __shared__ int h[NBKT];
    const int b = blockIdx.x;
    for (int i = TID; i < NBKT; i += 256) h[i] = 0;
    __syncthreads();
    const int e0 = b * CHE2, e1 = min(e0 + CHE2, NE);
    for (int i = e0 + TID; i < e1; i += 256) atomicAdd(&h[nl0[i] >> 6], 1);
    __syncthreads();
    for (int i = TID; i < NBKT; i += 256) { cntE[(size_t)i * NB2 + b] = (uchar)h[i]; h[i] = 0; }
    __syncthreads();
    const int t0 = b * CHT2, t1 = min(t0 + CHT2, NT);
    for (int i = t0 + TID; i < t1; i += 256) atomicAdd(&h[tidx[3 * i + 1] >> 6], 1);
    __syncthreads();
    for (int i = TID; i < NBKT; i += 256) cntT[(size_t)i * NB2 + b] = (uchar)h[i];
}

// Per-bucket exclusive scan across the 512 blocks -> bases (ushort) + bucket totals (int).
__global__ __launch_bounds__(256) void k_bscan(const uchar* __restrict__ cE,
                                               const uchar* __restrict__ cT,
                                               ushort* __restrict__ baseE,
                                               ushort* __restrict__ baseT,
                                               int* __restrict__ totEb,
                                               int* __restrict__ totTb) {
    const int lane = TID & 63;
    const int wv = TID >> 6;
    int task = blockIdx.x * 4 + wv;
    if (task >= 2 * NBKT) return;
    const bool isE = task < NBKT;
    const int k = isE ? task : task - NBKT;
    const uchar* src = isE ? cE : cT;
    ushort* dst = isE ? baseE : baseT;
    int* dT = isE ? totEb : totTb;
    int v[8], pre[8], s = 0;
    #pragma unroll
    for (int j = 0; j < 8; ++j) {
        v[j] = src[(size_t)k * NB2 + lane * 8 + j];
        pre[j] = s;
        s += v[j];
    }
    int incl = s;
    #pragma unroll
    for (int off = 1; off < 64; off <<= 1) {
        int t = __shfl_up(incl, off, 64);
        if (lane >= off) incl += t;
    }
    int excl = incl - s;
    #pragma unroll
    for (int j = 0; j < 8; ++j)
        dst[(size_t)k * NB2 + lane * 8 + j] = (ushort)(excl + pre[j]);
    if (lane == 63) dT[k] = incl;
}

__device__ void scan_one(const int* __restrict__ hist, int* __restrict__ start, int n) {
    __shared__ int wsum[16];
    __shared__ int carryS;
    const int lane = TID & 63;
    const int wv = TID >> 6;
    if (TID == 0) carryS = 0;
    __syncthreads();
    for (int base = 0; base < n; base += 1024) {
        int i = base + TID;
        int v = (i < n) ? hist[i] : 0;
        int acc = v;
        #pragma unroll
        for (int off = 1; off < 64; off <<= 1) {
            int t = __shfl_up(acc, off, 64);
            if (lane >= off) acc += t;
        }
        if (lane == 63) wsum[wv] = acc;
        __syncthreads();
        int woff = 0;
        for (int w = 0; w < wv; ++w) woff += wsum[w];
        int excl = carryS + woff + acc - v;
        if (i < n) start[i] = excl;
        __syncthreads();
        if (TID == 1023) carryS = excl + v;
        __syncthreads();
    }
}

__global__ __launch_bounds__(1024) void k_bktscan(const int* __restrict__ totEb, int* __restrict__ bksE,
                                                  const int* __restrict__ totTb, int* __restrict__ bksT) {
    if (blockIdx.x == 0) scan_one(totEb, bksE, NBKT);
    else                 scan_one(totTb, bksT, NBKT);
}

// Phase-1 placement into bucket regions (LDS cursors, near-coalesced stores).
__global__ __launch_bounds__(256) void k_bplace(const int* __restrict__ nl0,
                                                const int* __restrict__ nl1,
                                                const float* __restrict__ dist,
                                                const int* __restrict__ tidx,
                                                const float* __restrict__ angles,
                                                const float* __restrict__ rij,
                                                const float* __restrict__ rik,
                                                const ushort* __restrict__ baseE,
                                                const ushort* __restrict__ baseT,
                                                const int* __restrict__ bksE,
                                                const int* __restrict__ bksT,
                                                int2* __restrict__ eT,
                                                int2* __restrict__ tT) {
    __shared__ int cur[NBKT];
    const int b = blockIdx.x;
    for (int k = TID; k < NBKT; k += 256)
        cur[k] = bksE[k] + (int)baseE[(size_t)k * NB2 + b];
    __syncthreads();
    const int e0 = b * CHE2, e1 = min(e0 + CHE2, NE);
    for (int i = e0 + TID; i < e1; i += 256) {
        int n0 = nl0[i];
        int pos = atomicAdd(&cur[n0 >> 6], 1);
        uint tq = (uint)fmaf(dist[i], 209715.2f, 0.5f);   // d * (4096/5) * 256
        eT[pos] = make_int2((int)(tq | ((uint)(n0 & 63) << 26)), nl1[i]);
    }
    __syncthreads();
    for (int k = TID; k < NBKT; k += 256)
        cur[k] = bksT[k] + (int)baseT[(size_t)k * NB2 + b];
    __syncthreads();
    const int t0 = b * CHT2, tEnd = min(t0 + CHT2, NT);
    for (int i = t0 + TID; i < tEnd; i += 256) {
        int t1 = tidx[3 * i + 1];
        int pos = atomicAdd(&cur[t1 >> 6], 1);
        uint ab = ((uint)__half_as_ushort(__float2half_rn(rik[i])) << 16)
                | (uint)__half_as_ushort(__float2half_rn(rij[i]));
        uint cc = (uint)__half_as_ushort(__float2half_rn(__cosf(angles[i])))
                | ((uint)(t1 & 63) << 16);
        tT[pos] = make_int2((int)ab, (int)cc);
    }
}

// Phase-2: per bucket, exact node sort within the bucket window (L2-resident scatter).
__global__ __launch_bounds__(256) void k_nsort(const int2* __restrict__ eTs,
                                               const int2* __restrict__ tTs,
                                               const int* __restrict__ bksE,
                                               const int* __restrict__ bksT,
                                               const int* __restrict__ totEb,
                                               const int* __restrict__ totTb,
                                               int2* __restrict__ eS,
                                               int2* __restrict__ tS,
                                               int* __restrict__ startE,
                                               int* __restrict__ totE,
                                               int* __restrict__ startT,
                                               int* __restrict__ totT) {
    __shared__ int hist[64];
    __shared__ int cur[64];
    const bool isE = blockIdx.x < NBKT;
    const int bkt = isE ? blockIdx.x : blockIdx.x - NBKT;
    const int2* src = isE ? eTs : tTs;
    int2* dst = isE ? eS : tS;
    const int s0 = isE ? bksE[bkt] : bksT[bkt];
    const int cnt = isE ? totEb[bkt] : totTb[bkt];
    int* stX = isE ? startE : startT;
    int* ttX = isE ? totE : totT;
    if (TID < 64) hist[TID] = 0;
    __syncthreads();
    for (int i = TID; i < cnt; i += 256) {
        int2 p = src[s0 + i];
        int nlo = isE ? (int)(((uint)p.x >> 26) & 63u) : (int)(((uint)p.y >> 16) & 63u);
        atomicAdd(&hist[nlo], 1);
    }
    __syncthreads();
    if (TID < 64) {                    // exactly wave 0
        int v = hist[TID];
        int incl = v;
        #pragma unroll
        for (int off = 1; off < 64; off <<= 1) {
            int t = __shfl_up(incl, off, 64);
            if (TID >= off) incl += t;
        }
        int excl = incl - v;
        cur[TID] = s0 + excl;
        int node = bkt * 64 + TID;
        if (node < NN) { stX[node] = s0 + excl; ttX[node] = v; }
    }
    __syncthreads();
    for (int i = TID; i < cnt; i += 256) {
        int2 p = src[s0 + i];
        int nlo = isE ? (int)(((uint)p.x >> 26) & 63u) : (int)(((uint)p.y >> 16) & 63u);
        int pos = atomicAdd(&cur[nlo], 1);
        dst[pos] = p;
    }
}

// Edge consume, wave-per-node; staging pre-computes byte offsets + fr (lane-parallel).
__global__ __launch_bounds__(256) void k_edges_node(const int2* __restrict__ eS,
                                                    const int* __restrict__ startE,
                                                    const int* __restrict__ totE,
                                                    const ushort* __restrict__ hB,
                                                    const ushort* __restrict__ lutB,
                                                    float* __restrict__ agg) {
    __shared__ int4 stage[4][64];   // 4 KB, wave-private slots
    const int lane = TID & 63;
    const int wv = TID >> 6;
    const int c2b = lane << 2;      // byte offset of this lane's 2 cols (2 x bf16 = 4 B)
    for (int r = blockIdx.x * 4 + wv; r < NN; r += gridDim.x * 4) {
        const int s0 = startE[r];
        const int cnt = totE[r];
        float a0 = 0.f, a1 = 0.f;
        for (int base = 0; base < cnt; base += 64) {
            const int n = min(64, cnt - base);
            if (lane < n) {
                int2 p = eS[s0 + base + lane];
                uint tq = ((uint)p.x) & 0x03FFFFFFu;
                int idx = min((int)(tq >> 8), LUTN - 2);
                float fr = (float)(tq & 255u) * (1.0f / 256.0f);
                stage[wv][lane] = make_int4(idx * (C * 2), __float_as_int(fr),
                                            p.y * (C * 2), 0);
            }
            asm volatile("s_waitcnt lgkmcnt(0)" ::: "memory");
            #pragma unroll 8
            for (int i = 0; i < n; ++i) {
                int4 q = stage[wv][i];           // uniform address -> LDS broadcast
                float fr = __int_as_float(q.y);
                ushort2 A2 = *(const ushort2*)((const char*)lutB + q.x + c2b);
                ushort2 B2 = *(const ushort2*)((const char*)lutB + q.x + 256 + c2b);
                ushort2 H2 = *(const ushort2*)((const char*)hB + q.z + c2b);
                float ax = bf2f(A2.x), ay = bf2f(A2.y);
                float ox = fmaf(fr, bf2f(B2.x) - ax, ax);
                float oy = fmaf(fr, bf2f(B2.y) - ay, ay);
                a0 = fmaf(ox, bf2f(H2.x), a0);
                a1 = fmaf(oy, bf2f(H2.y), a1);
            }
            asm volatile("s_waitcnt lgkmcnt(0)" ::: "memory");  // reads done before overwrite
        }
        float2 o = {a0, a1};
        *(float2*)&agg[(size_t)r * C + (lane << 1)] = o;
    }
}

// Triplet consume: f32 pre-unpacked staging + softplus-correction LUT (no transcendentals),
// bf16-packed W3b2 in LDS (occupancy), epilogue matvec + atomic add.
__global__ __launch_bounds__(256) void k_trip_node(const int* __restrict__ startT,
                                                   const int* __restrict__ totT,
                                                   const int2* __restrict__ tS,
                                                   const float* __restrict__ W3b1,
                                                   const float* __restrict__ W3b2,
                                                   const float2* __restrict__ spLut,
                                                   const ushort* __restrict__ hB,
                                                   const int* __restrict__ nl0,
                                                   float* __restrict__ agg) {
    __shared__ uint w2p[64 * 64];    // 16 KB: packed {hi=col64+l, lo=col l} bf16
    __shared__ float2 spl[512];      // 4 KB
    __shared__ float4 stage[4][64];  // 4 KB, wave-private
    for (int i = TID; i < 512; i += 256) spl[i] = spLut[i];
    for (int i = TID; i < 4096; i += 256) {
        int k = i >> 6, l = i & 63;
        float lo = W3b2[k * C + l];
        float hi = W3b2[k * C + 64 + l];
        w2p[i] = ((uint)f2bf(hi) << 16) | (uint)f2bf(lo);
    }
    __syncthreads();
    const int lane = TID & 63;
    const int wv = TID >> 6;
    const float w1a = W3b1[lane];
    const float w1b = W3b1[64 + lane];
    const float w1c = W3b1[128 + lane];
    for (int r = blockIdx.x * 4 + wv; r < NN; r += gridDim.x * 4) {
        const int s0 = startT[r];
        const int cnt = totT[r];
        float usum = 0.f;
        for (int base = 0; base < cnt; base += 64) {
            const int n = min(64, cnt - base);
            if (lane < n) {
                uint2 p = ((const uint2*)tS)[s0 + base + lane];
                float4 f;
                f.x = h2f(p.x);          // rij
                f.y = h2f(p.x >> 16);    // rik
                f.z = h2f(p.y);          // cos(angle)
                f.w = 0.f;
                stage[wv][lane] = f;
            }
            asm volatile("s_waitcnt lgkmcnt(0)" ::: "memory");
            #pragma unroll 4
            for (int i = 0; i < n; ++i) {
                float4 p = stage[wv][i];         // uniform address -> broadcast
                float x = fmaf(p.x, w1a, fmaf(p.y, w1b, p.z * w1c));
                float t = fabsf(x) * 32.0f;
                int idx = min((int)t, 511);
                float fr = t - (float)idx;
                float2 vs = spl[idx];            // gather
                usum += fmaxf(x, 0.f) + fmaf(fr, vs.y, vs.x);
            }
            asm volatile("s_waitcnt lgkmcnt(0)" ::: "memory");
        }
        usum -= LN2 * (float)cnt;
        float o0 = 0.f, o1 = 0.f;
        #pragma unroll 8
        for (int k = 0; k < 64; ++k) {
            float uk = __shfl(usum, k, 64);
            uint wp = w2p[k * 64 + lane];
            float lo = __uint_as_float(wp << 16);
            float hi = __uint_as_float(wp & 0xFFFF0000u);
            o0 = fmaf(uk, lo, o0);
            o1 = fmaf(uk, hi, o1);
        }
        const int n0 = nl0[r];
        float h0 = bf2f(hB[(size_t)r * C + lane]);
        float h1 = bf2f(hB[(size_t)r * C + 64 + lane]);
        unsafeAtomicAdd(&agg[(size_t)n0 * C + lane], o0 * h0);
        unsafeAtomicAdd(&agg[(size_t)n0 * C + 64 + lane], o1 * h1);
    }
}

extern "C" void kernel_launch(void* const* d_in, const int* in_sizes, int n_in,
                              void* d_out, int out_size, void* d_ws, size_t ws_size,
                              hipStream_t stream) {
    const float* features = (const float*)d_in[0];
    const float* ndist    = (const float*)d_in[1];
    const int*   nlist    = (const int*)d_in[2];
    const int*   tidx     = (const int*)d_in[3];
    const float* angles   = (const float*)d_in[4];
    const float* rij      = (const float*)d_in[5];
    const float* rik      = (const float*)d_in[6];
    const float* W_pre    = (const float*)d_in[7];
    const float* W2b1     = (const float*)d_in[8];
    const float* W2b2     = (const float*)d_in[9];
    const float* W3b1     = (const float*)d_in[10];
    const float* W3b2     = (const float*)d_in[11];
    const float* W_post   = (const float*)d_in[12];
    float* out = (float*)d_out;

    char* w = (char*)d_ws;
    // agg (10.24 MB) region: first 5.12 MB aliases eT (dead before agg is written)
    float* agg    = (float*)w;
    int2* eT      = (int2*)w;
    w += (size_t)NN * C * 4;                                   // 10.24 MB
    ushort* hB    = (ushort*)w;  w += (size_t)NN * C * 2;      // 5.12 MB
    ushort* lutB  = (ushort*)w;  w += (size_t)LUTN * C * 2;    // 1.05 MB
    int2* eS      = (int2*)w;    w += (size_t)NE * 8;          // 5.12 MB
    int2* tS      = (int2*)w;    w += (size_t)NT * 8;          // 8 MB
    int2* tT      = (int2*)w;    w += (size_t)NT * 8;          // 8 MB
    uchar* cntE   = (uchar*)w;   w += (size_t)NBKT * NB2;      // 160 KB
    uchar* cntT   = (uchar*)w;   w += (size_t)NBKT * NB2;
    ushort* baseE = (ushort*)w;  w += (size_t)NBKT * NB2 * 2;  // 320 KB
    ushort* baseT = (ushort*)w;  w += (size_t)NBKT * NB2 * 2;
    int* totEb    = (int*)w;     w += 1280;
    int* totTb    = (int*)w;     w += 1280;
    int* bksE     = (int*)w;     w += 1280;
    int* bksT     = (int*)w;     w += 1280;
    int* startE   = (int*)w;     w += (size_t)NN * 4;
    int* totE     = (int*)w;     w += (size_t)NN * 4;
    int* startT   = (int*)w;     w += (size_t)NN * 4;
    int* totT     = (int*)w;     w += (size_t)NN * 4;
    float2* spLut = (float2*)w;  w += 512 * 8;                 // 4 KB

    const int* nl0 = nlist;
    const int* nl1 = nlist + NE;

    hipLaunchKernelGGL(k_gemm16b, dim3((NN + 15) / 16), dim3(256), 0, stream,
                       features, W_pre, hB, NN);
    hipLaunchKernelGGL(k_lut, dim3((LUTN + 7) / 8 + 1), dim3(256), 0, stream,
                       W2b1, W2b2, lutB, spLut);
    hipLaunchKernelGGL(k_bcount, dim3(NB2), dim3(256), 0, stream,
                       nl0, tidx, cntE, cntT);
    hipLaunchKernelGGL(k_bscan, dim3((2 * NBKT + 3) / 4), dim3(256), 0, stream,
                       cntE, cntT, baseE, baseT, totEb, totTb);
    hipLaunchKernelGGL(k_bktscan, dim3(2), dim3(1024), 0, stream,
                       totEb, bksE, totTb, bksT);
    hipLaunchKernelGGL(k_bplace, dim3(NB2), dim3(256), 0, stream,
                       nl0, nl1, ndist, tidx, angles, rij, rik,
                       baseE, baseT, bksE, bksT, eT, tT);
    hipLaunchKernelGGL(k_nsort, dim3(2 * NBKT), dim3(256), 0, stream,
                       eT, tT, bksE, bksT, totEb, totTb,
                       eS, tS, startE, totE, startT, totT);
    hipLaunchKernelGGL(k_edges_node, dim3(2500), dim3(256), 0, stream,
                       eS, startE, totE, hB, lutB, agg);
    hipLaunchKernelGGL(k_trip_node, dim3(2500), dim3(256), 0, stream,
                       startT, totT, tS, W3b1, W3b2, spLut, hB, nl0, agg);
    hipLaunchKernelGGL(k_gemm16f, dim3((NN + 15) / 16), dim3(256), 0, stream,
                       agg, W_post, out, NN);
}